// Round 6
// baseline (799.278 us; speedup 1.0000x reference)
//
#include <hip/hip_runtime.h>

// ---------------------------------------------------------------------------
// LlamaAttention_Tender: hidden(2048x4096) -> QKV proj -> RoPE -> int8 qdq(K,V)
// -> GQA causal attention (32 q-heads, 8 kv-heads, D=128) -> out proj.
// R8: attention TLP + softmax-overhead pass (GEMMs unchanged from R7):
//     - single-buffered K/V in LDS (48KB total w/ Ps) -> 3 blocks/CU
//       (launch_bounds(256,3) caps VGPR so 12 waves/CU co-reside);
//     - T14 reg-staging: tile t+1 prefetched into 32 VGPRs at compute start
//       (sched_barrier-pinned), vmcnt(0)+ds_write after the read-done
//       barrier -> stage latency hidden under compute, no per-step drain;
//     - T13 defer-max (THR=8): skip alpha/O-rescale unless
//       __any(pmax > mrow+8); P bounded by e^8, f32 accum headroom.
// ---------------------------------------------------------------------------

#define S_LEN 2048
#define HID 4096
#define NH 32
#define NKV 8
#define HD 128
#define QKV_N 6144   // 4096 q + 1024 k + 1024 v

typedef __bf16 bf16x8 __attribute__((ext_vector_type(8)));
typedef float f32x4 __attribute__((ext_vector_type(4)));

__device__ __forceinline__ unsigned short f2b(float f) {
  unsigned int u = __float_as_uint(f);
  u += 0x7fffu + ((u >> 16) & 1u);   // round-to-nearest-even
  return (unsigned short)(u >> 16);
}
__device__ __forceinline__ float b2f(unsigned short h) {
  return __uint_as_float(((unsigned int)h) << 16);
}
// async global->LDS, 16B per lane. LDS dst must be wave-uniform (lane*16 implicit).
__device__ __forceinline__ void gl_lds16(const void* g, void* l) {
  __builtin_amdgcn_global_load_lds(
      (__attribute__((address_space(1))) void*)g,
      (__attribute__((address_space(3))) void*)l, 16, 0, 0);
}
// compiler-opaque LDS b128 read (no alias info -> no auto vmcnt drains).
__device__ __forceinline__ bf16x8 ds_read128(const void* p) {
  bf16x8 r;
  unsigned a = (unsigned)(unsigned long long)
      (__attribute__((address_space(3))) const void*)p;
  asm volatile("ds_read_b128 %0, %1" : "=v"(r) : "v"(a));
  return r;
}
// LDS bank-spread swizzle: permutes 16B chunks within a 128B row; involution.
__device__ __forceinline__ int swz(int row) {
  return ((row & 7) << 4) ^ (((row >> 3) & 1) << 5);
}
// barrier without the __syncthreads vmcnt(0) drain; asm fences stop IR motion
__device__ __forceinline__ void barrier_np() {
  asm volatile("" ::: "memory");
  __builtin_amdgcn_s_barrier();
  asm volatile("" ::: "memory");
}
#define WAITL0                                            \
  do {                                                    \
    asm volatile("s_waitcnt lgkmcnt(0)" ::: "memory");    \
    __builtin_amdgcn_sched_barrier(0);                    \
  } while (0)

// ---------------------------------------------------------------- cast fp32->bf16
__global__ __launch_bounds__(256) void cast_kernel(const float* __restrict__ src,
                                                   unsigned short* __restrict__ dst,
                                                   int n4) {
  int i = blockIdx.x * 256 + threadIdx.x;
  if (i >= n4) return;
  float4 v = ((const float4*)src)[i];
  ushort4 o;
  o.x = f2b(v.x); o.y = f2b(v.y); o.z = f2b(v.z); o.w = f2b(v.w);
  ((ushort4*)dst)[i] = o;
}

// --------------------------------- B^T GEMM, 128xBN tile, 4 waves, 2 blocks/CU
// C[M,N] = A[M,K]*B[N,K]^T. 256 thr = 4 waves (2Mx2N), per-wave out 64x(BN/2).
// LDS per buffer: A 16KB + B BN*128B; double-buffered. BK=64, NT=K/64.
// CMODE: 0 = f32 store, 1 = bf16 store.
template <int BN, int CMODE>
__global__ __launch_bounds__(256, 2) void gemm_bt(const unsigned short* __restrict__ A,
                                                  const unsigned short* __restrict__ B,
                                                  void* __restrict__ Cout,
                                                  int M, int N, int K) {
  constexpr int NI = BN / 32;                 // per-wave ni count (6 or 4)
  constexpr int BSTRIDE = 16384 + BN * 128;   // per-buffer LDS bytes
  __shared__ __align__(16) char lds[2 * BSTRIDE];
  const int tid = threadIdx.x;
  const int lane = tid & 63, wave = tid >> 6;
  const int quad = lane >> 4, l16 = lane & 15;
  const int wave_m = wave >> 1, wave_n = wave & 1;
  const long row0 = (long)blockIdx.y * 128;
  const long col0 = (long)blockIdx.x * BN;
  const int NT = K >> 6;
  const long rowstride = (long)K * 2;

  f32x4 acc[4][NI] = {};

  // stage A half-tile (64 rows, 8KB): 2 gl_lds per wave
  auto stageA = [&](int T, int h, int buf) {
    if (T >= NT) return;
    char* dst = lds + buf * BSTRIDE + h * 8192 + wave * 1024;
    const char* src = (const char*)A + (row0 + h * 64) * rowstride + (long)T * 128;
#pragma unroll
    for (int c = 0; c < 2; ++c) {
      int b = c * 4096 + wave * 1024 + lane * 16;
      int r = b >> 7, cb = b & 127;
      gl_lds16(src + (long)r * rowstride + (cb ^ swz(r)), dst + c * 4096);
    }
  };
  // stage B half-tile (BN/2 rows): BN/64 gl_lds per wave
  auto stageB = [&](int T, int h, int buf) {
    if (T >= NT) return;
    char* dst = lds + buf * BSTRIDE + 16384 + h * (BN * 64) + wave * 1024;
    const char* src = (const char*)B + (col0 + h * (BN / 2)) * rowstride + (long)T * 128;
#pragma unroll
    for (int c = 0; c < BN / 64; ++c) {
      int b = c * 4096 + wave * 1024 + lane * 16;
      int r = b >> 7, cb = b & 127;
      gl_lds16(src + (long)r * rowstride + (cb ^ swz(r)), dst + c * 4096);
    }
  };
  // counted vmcnt: HOPS = ops per (A-half + B-half) stage pair = 2 + BN/64
  auto fence_steady = [&]() {
    if (BN == 192) asm volatile("s_waitcnt vmcnt(5)" ::: "memory");
    else           asm volatile("s_waitcnt vmcnt(4)" ::: "memory");
  };

  // prologue: T0 h0, T0 h1, T1 h0 -> fence completes T0 fully, carry = h0(T1)
  stageA(0, 0, 0); stageB(0, 0, 0);
  stageA(0, 1, 0); stageB(0, 1, 0);
  stageA(1, 0, 1); stageB(1, 0, 1);
  fence_steady();

  for (int g = 0; g < NT; ++g) {
    const int buf = g & 1;
    barrier_np();                          // #1: all waves fenced; buf data ready
    stageA(g + 1, 1, buf ^ 1);             // h1 of next tile -> other buffer
    stageB(g + 1, 1, buf ^ 1);

    bf16x8 a[2][4], b[2][NI];
#pragma unroll
    for (int mi = 0; mi < 4; ++mi) {
      int row = wave_m * 64 + mi * 16 + l16;
      const char* rp = lds + buf * BSTRIDE + row * 128;
      int sw = swz(row);
      a[0][mi] = ds_read128(rp + ((quad * 16) ^ sw));
      a[1][mi] = ds_read128(rp + ((64 + quad * 16) ^ sw));
    }
#pragma unroll
    for (int ni = 0; ni < NI; ++ni) {
      int row = wave_n * (BN / 2) + ni * 16 + l16;
      const char* rp = lds + buf * BSTRIDE + 16384 + row * 128;
      int sw = swz(row);
      b[0][ni] = ds_read128(rp + ((quad * 16) ^ sw));
      b[1][ni] = ds_read128(rp + ((64 + quad * 16) ^ sw));
    }
    WAITL0;                                // my reads done
    barrier_np();                          // #2: everyone's reads done
    stageA(g + 2, 0, buf);                 // overwrite h0 of current buf
    stageB(g + 2, 0, buf);

    __builtin_amdgcn_s_setprio(1);
#pragma unroll
    for (int ks = 0; ks < 2; ++ks)
#pragma unroll
      for (int mi = 0; mi < 4; ++mi)
#pragma unroll
        for (int ni = 0; ni < NI; ++ni)
          acc[mi][ni] = __builtin_amdgcn_mfma_f32_16x16x32_bf16(
              a[ks][mi], b[ks][ni], acc[mi][ni], 0, 0, 0);
    __builtin_amdgcn_s_setprio(0);

    if (g + 2 < NT) fence_steady();
    else            asm volatile("s_waitcnt vmcnt(0)" ::: "memory");
  }

  // epilogue: C write (C/D layout: col=l16, row=quad*4+r per 16x16 frag)
#pragma unroll
  for (int mi = 0; mi < 4; ++mi)
#pragma unroll
    for (int ni = 0; ni < NI; ++ni)
#pragma unroll
      for (int r = 0; r < 4; ++r) {
        long row = row0 + wave_m * 64 + mi * 16 + quad * 4 + r;
        long col = col0 + wave_n * (BN / 2) + ni * 16 + l16;
        float v = acc[mi][ni][r];
        if (CMODE == 1) ((unsigned short*)Cout)[row * N + col] = f2b(v);
        else            ((float*)Cout)[row * N + col] = v;
      }
}

// ------------------------------------------- RoPE + sym int8 quant-dequant + split
// qkv[2048][6144] bf16 -> Qb[32][2048][128], Kb[8][2048][128], Vb[8][2048][128]
__global__ __launch_bounds__(256) void postproc(const unsigned short* __restrict__ qkv,
                                                const int* __restrict__ pos_ids,
                                                unsigned short* __restrict__ Qb,
                                                unsigned short* __restrict__ Kb,
                                                unsigned short* __restrict__ Vb) {
  const int s = blockIdx.x;
  const int lane = threadIdx.x & 63, wave = threadIdx.x >> 6;
  const float pos = (float)pos_ids[s];
  // inv_freq = 10000^(-lane/64) = exp(-lane * ln(10000)/64); pair (d, d+64)
  const float invf = expf(-(float)lane * 0.14391156831212787f);
  const float ang = pos * invf;
  const float ca = cosf(ang), sa = sinf(ang);

  for (int r = wave; r < 48; r += 4) {
    if (r < 32) {                 // Q head r: rope only
      const unsigned short* src = qkv + (long)s * QKV_N + r * HD;
      float x0 = b2f(src[lane]), x1 = b2f(src[lane + 64]);
      unsigned short* dst = Qb + ((long)r * S_LEN + s) * HD;
      dst[lane]      = f2b(x0 * ca - x1 * sa);
      dst[lane + 64] = f2b(x1 * ca + x0 * sa);
    } else if (r < 40) {          // K head r-32: rope then quant-dequant
      int h = r - 32;
      const unsigned short* src = qkv + (long)s * QKV_N + 4096 + h * HD;
      float x0 = b2f(src[lane]), x1 = b2f(src[lane + 64]);
      float y0 = x0 * ca - x1 * sa;
      float y1 = x1 * ca + x0 * sa;
      float m = fmaxf(fabsf(y0), fabsf(y1));
      for (int off = 32; off; off >>= 1) m = fmaxf(m, __shfl_xor(m, off, 64));
      float scale = fmaxf(m / 127.0f, 1e-9f);
      float q0 = fminf(fmaxf(rintf(y0 / scale), -128.f), 127.f);
      float q1 = fminf(fmaxf(rintf(y1 / scale), -128.f), 127.f);
      unsigned short* dst = Kb + ((long)h * S_LEN + s) * HD;
      dst[lane]      = f2b(q0 * scale);
      dst[lane + 64] = f2b(q1 * scale);
    } else {                      // V head r-40: quant-dequant only
      int h = r - 40;
      const unsigned short* src = qkv + (long)s * QKV_N + 5120 + h * HD;
      float x0 = b2f(src[lane]), x1 = b2f(src[lane + 64]);
      float m = fmaxf(fabsf(x0), fabsf(x1));
      for (int off = 32; off; off >>= 1) m = fmaxf(m, __shfl_xor(m, off, 64));
      float scale = fmaxf(m / 127.0f, 1e-9f);
      float q0 = fminf(fmaxf(rintf(x0 / scale), -128.f), 127.f);
      float q1 = fminf(fmaxf(rintf(x1 / scale), -128.f), 127.f);
      unsigned short* dst = Vb + ((long)h * S_LEN + s) * HD;
      dst[lane]      = f2b(q0 * scale);
      dst[lane + 64] = f2b(q1 * scale);
    }
  }
}

// -------------------------------------------------- V transpose: [h][s][d]->[h][d][s]
__global__ __launch_bounds__(256) void transpose_v(const unsigned short* __restrict__ Vb,
                                                   unsigned short* __restrict__ Vtb) {
  __shared__ unsigned short t[64][136];
  const int h = blockIdx.x >> 5, st = blockIdx.x & 31;
  const int tid = threadIdx.x;
  const long vbase = (long)h * S_LEN * HD;
#pragma unroll
  for (int p = 0; p < 8; ++p) {
    int e = p * 1024 + tid * 4;
    int sl = e >> 7, d = e & 127;
    ushort4 v = *(const ushort4*)(Vb + vbase + (long)(st * 64 + sl) * HD + d);
    t[sl][d] = v.x; t[sl][d + 1] = v.y; t[sl][d + 2] = v.z; t[sl][d + 3] = v.w;
  }
  __syncthreads();
  const long tbase = (long)h * HD * S_LEN;
#pragma unroll
  for (int p = 0; p < 8; ++p) {
    int o = p * 1024 + tid * 4;
    int d = o >> 6, sl = o & 63;
    ushort4 v;
    v.x = t[sl][d]; v.y = t[sl + 1][d]; v.z = t[sl + 2][d]; v.w = t[sl + 3][d];
    *(ushort4*)(Vtb + tbase + (long)d * S_LEN + st * 64 + sl) = v;
  }
}

// ------------------------------------------------------------- flash attention
// Block = (head, 128-row q-tile), 4 waves x 32 q-rows. KVBLK=64.
// R8: single-buffered K/V (LDS 48KB: K 16K @0, Vt 16K @16384, Ps 16K @32768)
// -> 3 blocks/CU. Tile t+1 prefetched to 32 VGPRs at compute start (T14);
// vmcnt(0)+ds_write AFTER the read-done barrier. Defer-max (T13, THR=8).
// Both-sides XOR swizzle on K/Vt/Ps unchanged.
__global__ __launch_bounds__(256, 3) void attn_kernel(const unsigned short* __restrict__ Qb,
                                                      const unsigned short* __restrict__ Kb,
                                                      const unsigned short* __restrict__ Vtb,
                                                      unsigned short* __restrict__ Ob) {
  __shared__ __align__(16) char lds[49152];

  const int bx = blockIdx.x;
  const int p8 = bx & 1;
  const int g = (bx >> 1) & 7;
  const int b8 = bx >> 8;
  const int qt = (p8 ^ b8) ? (15 - g) : g;
  const int h = ((bx >> 4) & 15) + 16 * b8;
  const int hk = h >> 2;                        // GQA: 4 q-heads per kv-head
  const int tid = threadIdx.x;
  const int lane = tid & 63, wave = tid >> 6;
  const int quad = lane >> 4, l16 = lane & 15;

  // Q fragments for this wave's 32 rows (A-operand layout), from global
  bf16x8 qf[2][4];
  {
    const unsigned short* qb =
        Qb + ((long)h * S_LEN + qt * 128 + wave * 32 + l16) * HD + quad * 8;
#pragma unroll
    for (int mi = 0; mi < 2; ++mi)
#pragma unroll
      for (int ks = 0; ks < 4; ++ks)
        qf[mi][ks] = *(const bf16x8*)(qb + mi * 16 * HD + ks * 32);
  }

  f32x4 O[2][8] = {};
  float mrow[2][4], lrow[2][4];
#pragma unroll
  for (int mi = 0; mi < 2; ++mi)
#pragma unroll
    for (int r = 0; r < 4; ++r) { mrow[mi][r] = -1e30f; lrow[mi][r] = 0.f; }

  const char* Kg = (const char*)(Kb + (long)hk * S_LEN * HD);
  const char* Vg = (const char*)(Vtb + (long)hk * HD * S_LEN);
  char* PsB = lds + 32768;
  const float sscale = 0.08838834764831845f;  // 1/sqrt(128)
  const int nsteps = 2 * qt + 2;              // 64-key steps

  // T14 prefetch regs: 4x16B K + 4x16B V per thread (same pre-swizzled
  // global addresses and LDS image as the old gl_lds16 staging).
  int4 kpf[4], vpf[4];
  auto loadRegs = [&](int step) {
    const char* ks = Kg + (long)step * 16384;
    const char* vs = Vg + (long)step * 128;
#pragma unroll
    for (int c = 0; c < 4; ++c) {
      int f = c * 4096 + tid * 16;
      int kr = f >> 8, kb = f & 255;
      kpf[c] = *(const int4*)(ks + kr * 256 + (kb ^ swz(kr)));
      int d = f >> 7, vb = f & 127;
      vpf[c] = *(const int4*)(vs + (long)d * (S_LEN * 2) + (vb ^ swz(d)));
    }
  };
  auto writeLDS = [&]() {
#pragma unroll
    for (int c = 0; c < 4; ++c) {
      *(int4*)(lds + c * 4096 + tid * 16) = kpf[c];
      *(int4*)(lds + 16384 + c * 4096 + tid * 16) = vpf[c];
    }
  };

  // prologue: tile 0 -> regs -> LDS
  loadRegs(0);
  asm volatile("s_waitcnt vmcnt(0)" ::: "memory");
  writeLDS();
  asm volatile("s_waitcnt lgkmcnt(0)" ::: "memory");

  for (int t = 0; t < nsteps; ++t) {
    barrier_np();                       // all waves' tile-t writes visible
    if (t + 1 < nsteps) {
      loadRegs(t + 1);                  // issue early; completes under compute
      __builtin_amdgcn_sched_barrier(0);
    }
    const char* Ks = lds;
    const char* Vs = lds + 16384;

    // ---- S = Q K^T over 64 keys (4 ni of 16)
    f32x4 S[2][4] = {};
    __builtin_amdgcn_s_setprio(1);
#pragma unroll
    for (int ni = 0; ni < 4; ++ni) {
      const int row = ni * 16 + l16;
      const char* kr = Ks + row * 256;
      const int sw = swz(row);
      const int q16 = quad * 16;
      bf16x8 kf0 = *(const bf16x8*)(kr + ((q16 + 0)   ^ sw));
      bf16x8 kf1 = *(const bf16x8*)(kr + ((q16 + 64)  ^ sw));
      bf16x8 kf2 = *(const bf16x8*)(kr + ((q16 + 128) ^ sw));
      bf16x8 kf3 = *(const bf16x8*)(kr + ((q16 + 192) ^ sw));
      S[0][ni] = __builtin_amdgcn_mfma_f32_16x16x32_bf16(qf[0][0], kf0, S[0][ni], 0, 0, 0);
      S[1][ni] = __builtin_amdgcn_mfma_f32_16x16x32_bf16(qf[1][0], kf0, S[1][ni], 0, 0, 0);
      S[0][ni] = __builtin_amdgcn_mfma_f32_16x16x32_bf16(qf[0][1], kf1, S[0][ni], 0, 0, 0);
      S[1][ni] = __builtin_amdgcn_mfma_f32_16x16x32_bf16(qf[1][1], kf1, S[1][ni], 0, 0, 0);
      S[0][ni] = __builtin_amdgcn_mfma_f32_16x16x32_bf16(qf[0][2], kf2, S[0][ni], 0, 0, 0);
      S[1][ni] = __builtin_amdgcn_mfma_f32_16x16x32_bf16(qf[1][2], kf2, S[1][ni], 0, 0, 0);
      S[0][ni] = __builtin_amdgcn_mfma_f32_16x16x32_bf16(qf[0][3], kf3, S[0][ni], 0, 0, 0);
      S[1][ni] = __builtin_amdgcn_mfma_f32_16x16x32_bf16(qf[1][3], kf3, S[1][ni], 0, 0, 0);
    }
    __builtin_amdgcn_s_setprio(0);

    // ---- scale + causal mask + row max
    const bool diag = (t >= 2 * qt);
    const int qrow_base = qt * 128 + wave * 32;
    float rmax[2][4];
#pragma unroll
    for (int mi = 0; mi < 2; ++mi)
#pragma unroll
      for (int r = 0; r < 4; ++r) rmax[mi][r] = -1e30f;
#pragma unroll
    for (int mi = 0; mi < 2; ++mi)
#pragma unroll
      for (int ni = 0; ni < 4; ++ni) {
        int col = t * 64 + ni * 16 + l16;
#pragma unroll
        for (int r = 0; r < 4; ++r) {
          int row = qrow_base + mi * 16 + quad * 4 + r;
          float v = S[mi][ni][r] * sscale;
          if (diag && col > row) v = -1e9f;
          S[mi][ni][r] = v;
          rmax[mi][r] = fmaxf(rmax[mi][r], v);
        }
      }

    // ---- defer-max (T13): rescale only when some row grew past mrow+8
    bool need = false;
    float pmax[2][4];
#pragma unroll
    for (int mi = 0; mi < 2; ++mi)
#pragma unroll
      for (int r = 0; r < 4; ++r) {
        float v = rmax[mi][r];
        v = fmaxf(v, __shfl_xor(v, 1, 64));
        v = fmaxf(v, __shfl_xor(v, 2, 64));
        v = fmaxf(v, __shfl_xor(v, 4, 64));
        v = fmaxf(v, __shfl_xor(v, 8, 64));
        pmax[mi][r] = v;
        need = need || (v > mrow[mi][r] + 8.0f);
      }
    if (__any(need)) {
      float alpha[2][4];
#pragma unroll
      for (int mi = 0; mi < 2; ++mi)
#pragma unroll
        for (int r = 0; r < 4; ++r) {
          float mnew = fmaxf(mrow[mi][r], pmax[mi][r]);
          alpha[mi][r] = __expf(mrow[mi][r] - mnew);
          mrow[mi][r] = mnew;
          lrow[mi][r] *= alpha[mi][r];
        }
#pragma unroll
      for (int mi = 0; mi < 2; ++mi)
#pragma unroll
        for (int ni = 0; ni < 8; ++ni)
#pragma unroll
          for (int r = 0; r < 4; ++r) O[mi][ni][r] *= alpha[mi][r];
    }

    // ---- P = exp(S - m) -> wave-local swizzled LDS rows, accumulate sums
    float rsum[2][4] = {};
#pragma unroll
    for (int mi = 0; mi < 2; ++mi)
#pragma unroll
      for (int ni = 0; ni < 4; ++ni)
#pragma unroll
        for (int r = 0; r < 4; ++r) {
          float p = __expf(S[mi][ni][r] - mrow[mi][r]);
          rsum[mi][r] += p;
          int prow = wave * 32 + mi * 16 + quad * 4 + r;
          int pcol2 = (ni * 16 + l16) * 2;
          *(unsigned short*)(PsB + prow * 128 + (pcol2 ^ swz(prow))) = f2b(p);
        }
#pragma unroll
    for (int mi = 0; mi < 2; ++mi)
#pragma unroll
      for (int r = 0; r < 4; ++r) {
        float v = rsum[mi][r];
        v += __shfl_xor(v, 1, 64);
        v += __shfl_xor(v, 2, 64);
        v += __shfl_xor(v, 4, 64);
        v += __shfl_xor(v, 8, 64);
        lrow[mi][r] += v;
      }

    // ---- O += P V : P A-frags from wave-local LDS, Vt B-frags from LDS tile
    bf16x8 pf[2][2];
#pragma unroll
    for (int mi = 0; mi < 2; ++mi)
#pragma unroll
      for (int ks2 = 0; ks2 < 2; ++ks2) {
        int prow = wave * 32 + mi * 16 + l16;
        pf[mi][ks2] = *(const bf16x8*)(PsB + prow * 128 +
                                       ((ks2 * 64 + quad * 16) ^ swz(prow)));
      }
    __builtin_amdgcn_s_setprio(1);
#pragma unroll
    for (int ni = 0; ni < 8; ++ni) {
      const int row = ni * 16 + l16;
      const char* vr = Vs + row * 128;
      const int sw = swz(row);
      const int q16 = quad * 16;
      bf16x8 vf0 = *(const bf16x8*)(vr + ((q16 + 0)  ^ sw));
      bf16x8 vf1 = *(const bf16x8*)(vr + ((q16 + 64) ^ sw));
      O[0][ni] = __builtin_amdgcn_mfma_f32_16x16x32_bf16(pf[0][0], vf0, O[0][ni], 0, 0, 0);
      O[1][ni] = __builtin_amdgcn_mfma_f32_16x16x32_bf16(pf[1][0], vf0, O[1][ni], 0, 0, 0);
      O[0][ni] = __builtin_amdgcn_mfma_f32_16x16x32_bf16(pf[0][1], vf1, O[0][ni], 0, 0, 0);
      O[1][ni] = __builtin_amdgcn_mfma_f32_16x16x32_bf16(pf[1][1], vf1, O[1][ni], 0, 0, 0);
    }
    __builtin_amdgcn_s_setprio(0);

    barrier_np();                       // all waves done reading tile t
    if (t + 1 < nsteps) {
      asm volatile("s_waitcnt vmcnt(0)" ::: "memory");
      writeLDS();                       // tile t+1 -> LDS
      asm volatile("s_waitcnt lgkmcnt(0)" ::: "memory");
    }
  }

  // normalize + store bf16 at [s][h*128+d]
#pragma unroll
  for (int mi = 0; mi < 2; ++mi)
#pragma unroll
    for (int r = 0; r < 4; ++r) {
      float inv = 1.0f / lrow[mi][r];
      long srow = qt * 128 + wave * 32 + mi * 16 + quad * 4 + r;
#pragma unroll
      for (int ni = 0; ni < 8; ++ni) {
        long col = (long)h * HD + ni * 16 + l16;
        Ob[srow * (long)HID + col] = f2b(O[mi][ni][r] * inv);
      }
    }
}

// ---------------------------------------------------------------------------
extern "C" void kernel_launch(void* const* d_in, const int* in_sizes, int n_in,
                              void* d_out, int out_size, void* d_ws, size_t ws_size,
                              hipStream_t stream) {
  const float* hidden = (const float*)d_in[0];
  const float* wq = (const float*)d_in[1];
  const float* wk = (const float*)d_in[2];
  const float* wv = (const float*)d_in[3];
  const float* wo = (const float*)d_in[4];
  const int* pos = (const int*)d_in[5];
  float* out = (float*)d_out;

  // workspace layout (bytes); total 138,412,032. Overlays: Qb=hid_b (hid dead
  // after GEMM1), attn_b=qkv_b (qkv dead after postproc).
  char* ws = (char*)d_ws;
  unsigned short* wqkv_b = (unsigned short*)(ws);               // 50,331,648
  unsigned short* wo_b   = (unsigned short*)(ws + 50331648);    // 33,554,432
  unsigned short* hid_b  = (unsigned short*)(ws + 83886080);    // 16,777,216
  unsigned short* qkv_b  = (unsigned short*)(ws + 100663296);   // 25,165,824
  unsigned short* Kb     = (unsigned short*)(ws + 125829120);   //  4,194,304
  unsigned short* Vb     = (unsigned short*)(ws + 130023424);   //  4,194,304
  unsigned short* Vtb    = (unsigned short*)(ws + 134217728);   //  4,194,304
  unsigned short* Qb     = hid_b;
  unsigned short* attn_b = qkv_b;

  cast_kernel<<<8388608 / 1024, 256, 0, stream>>>(hidden, hid_b, 8388608 / 4);
  cast_kernel<<<16777216 / 1024, 256, 0, stream>>>(wq, wqkv_b, 16777216 / 4);
  cast_kernel<<<4194304 / 1024, 256, 0, stream>>>(wk, wqkv_b + 16777216, 4194304 / 4);
  cast_kernel<<<4194304 / 1024, 256, 0, stream>>>(wv, wqkv_b + 20971520, 4194304 / 4);
  cast_kernel<<<16777216 / 1024, 256, 0, stream>>>(wo, wo_b, 16777216 / 4);

  // QKV: 128x192 tiles -> grid 32x16 = 512 blocks = 2/CU, 100% fill
  gemm_bt<192, 1><<<dim3(QKV_N / 192, S_LEN / 128), 256, 0, stream>>>(
      hid_b, wqkv_b, (void*)qkv_b, S_LEN, QKV_N, HID);

  postproc<<<S_LEN, 256, 0, stream>>>(qkv_b, pos, Qb, Kb, Vb);
  transpose_v<<<NKV * 32, 256, 0, stream>>>(Vb, Vtb);
  attn_kernel<<<NH * 16, 256, 0, stream>>>(Qb, Kb, Vtb, attn_b);

  // out-proj: 128x128 tiles -> grid 32x16 = 512 blocks = 2/CU, 100% fill
  gemm_bt<128, 0><<<dim3(HID / 128, S_LEN / 128), 256, 0, stream>>>(
      attn_b, wo_b, (void*)out, S_LEN, HID, HID);
}

// Round 7
// 542.427 us; speedup vs baseline: 1.4735x; 1.4735x over previous
//
#include <hip/hip_runtime.h>

// ---------------------------------------------------------------------------
// LlamaAttention_Tender: hidden(2048x4096) -> QKV proj -> RoPE -> int8 qdq(K,V)
// -> GQA causal attention (32 q-heads, 8 kv-heads, D=128) -> out proj.
// R9: R8's spill fixed. R8's launch_bounds(256,3) VGPR cap caused inner-loop
//     scratch spills (WRITE_SIZE 378MB) which thrashed L2 (FETCH 333MB).
//     Now: launch_bounds(256,2) (no cap-induced spill; occupancy follows
//     natural VGPR count: <=170 -> 3 blocks/CU with the 48KB LDS);
//     T14 prefetch issue moved AFTER QK^T (peak live regs ~165, not ~190);
//     defer-max (T13) and all swizzles unchanged. GEMMs = R7 (proven).
// ---------------------------------------------------------------------------

#define S_LEN 2048
#define HID 4096
#define NH 32
#define NKV 8
#define HD 128
#define QKV_N 6144   // 4096 q + 1024 k + 1024 v

typedef __bf16 bf16x8 __attribute__((ext_vector_type(8)));
typedef float f32x4 __attribute__((ext_vector_type(4)));

__device__ __forceinline__ unsigned short f2b(float f) {
  unsigned int u = __float_as_uint(f);
  u += 0x7fffu + ((u >> 16) & 1u);   // round-to-nearest-even
  return (unsigned short)(u >> 16);
}
__device__ __forceinline__ float b2f(unsigned short h) {
  return __uint_as_float(((unsigned int)h) << 16);
}
// async global->LDS, 16B per lane. LDS dst must be wave-uniform (lane*16 implicit).
__device__ __forceinline__ void gl_lds16(const void* g, void* l) {
  __builtin_amdgcn_global_load_lds(
      (__attribute__((address_space(1))) void*)g,
      (__attribute__((address_space(3))) void*)l, 16, 0, 0);
}
// compiler-opaque LDS b128 read (no alias info -> no auto vmcnt drains).
__device__ __forceinline__ bf16x8 ds_read128(const void* p) {
  bf16x8 r;
  unsigned a = (unsigned)(unsigned long long)
      (__attribute__((address_space(3))) const void*)p;
  asm volatile("ds_read_b128 %0, %1" : "=v"(r) : "v"(a));
  return r;
}
// LDS bank-spread swizzle: permutes 16B chunks within a 128B row; involution.
__device__ __forceinline__ int swz(int row) {
  return ((row & 7) << 4) ^ (((row >> 3) & 1) << 5);
}
// barrier without the __syncthreads vmcnt(0) drain; asm fences stop IR motion
__device__ __forceinline__ void barrier_np() {
  asm volatile("" ::: "memory");
  __builtin_amdgcn_s_barrier();
  asm volatile("" ::: "memory");
}
#define WAITL0                                            \
  do {                                                    \
    asm volatile("s_waitcnt lgkmcnt(0)" ::: "memory");    \
    __builtin_amdgcn_sched_barrier(0);                    \
  } while (0)

// ---------------------------------------------------------------- cast fp32->bf16
__global__ __launch_bounds__(256) void cast_kernel(const float* __restrict__ src,
                                                   unsigned short* __restrict__ dst,
                                                   int n4) {
  int i = blockIdx.x * 256 + threadIdx.x;
  if (i >= n4) return;
  float4 v = ((const float4*)src)[i];
  ushort4 o;
  o.x = f2b(v.x); o.y = f2b(v.y); o.z = f2b(v.z); o.w = f2b(v.w);
  ((ushort4*)dst)[i] = o;
}

// --------------------------------- B^T GEMM, 128xBN tile, 4 waves, 2 blocks/CU
// C[M,N] = A[M,K]*B[N,K]^T. 256 thr = 4 waves (2Mx2N), per-wave out 64x(BN/2).
// LDS per buffer: A 16KB + B BN*128B; double-buffered. BK=64, NT=K/64.
// CMODE: 0 = f32 store, 1 = bf16 store.
template <int BN, int CMODE>
__global__ __launch_bounds__(256, 2) void gemm_bt(const unsigned short* __restrict__ A,
                                                  const unsigned short* __restrict__ B,
                                                  void* __restrict__ Cout,
                                                  int M, int N, int K) {
  constexpr int NI = BN / 32;                 // per-wave ni count (6 or 4)
  constexpr int BSTRIDE = 16384 + BN * 128;   // per-buffer LDS bytes
  __shared__ __align__(16) char lds[2 * BSTRIDE];
  const int tid = threadIdx.x;
  const int lane = tid & 63, wave = tid >> 6;
  const int quad = lane >> 4, l16 = lane & 15;
  const int wave_m = wave >> 1, wave_n = wave & 1;
  const long row0 = (long)blockIdx.y * 128;
  const long col0 = (long)blockIdx.x * BN;
  const int NT = K >> 6;
  const long rowstride = (long)K * 2;

  f32x4 acc[4][NI] = {};

  // stage A half-tile (64 rows, 8KB): 2 gl_lds per wave
  auto stageA = [&](int T, int h, int buf) {
    if (T >= NT) return;
    char* dst = lds + buf * BSTRIDE + h * 8192 + wave * 1024;
    const char* src = (const char*)A + (row0 + h * 64) * rowstride + (long)T * 128;
#pragma unroll
    for (int c = 0; c < 2; ++c) {
      int b = c * 4096 + wave * 1024 + lane * 16;
      int r = b >> 7, cb = b & 127;
      gl_lds16(src + (long)r * rowstride + (cb ^ swz(r)), dst + c * 4096);
    }
  };
  // stage B half-tile (BN/2 rows): BN/64 gl_lds per wave
  auto stageB = [&](int T, int h, int buf) {
    if (T >= NT) return;
    char* dst = lds + buf * BSTRIDE + 16384 + h * (BN * 64) + wave * 1024;
    const char* src = (const char*)B + (col0 + h * (BN / 2)) * rowstride + (long)T * 128;
#pragma unroll
    for (int c = 0; c < BN / 64; ++c) {
      int b = c * 4096 + wave * 1024 + lane * 16;
      int r = b >> 7, cb = b & 127;
      gl_lds16(src + (long)r * rowstride + (cb ^ swz(r)), dst + c * 4096);
    }
  };
  // counted vmcnt: HOPS = ops per (A-half + B-half) stage pair = 2 + BN/64
  auto fence_steady = [&]() {
    if (BN == 192) asm volatile("s_waitcnt vmcnt(5)" ::: "memory");
    else           asm volatile("s_waitcnt vmcnt(4)" ::: "memory");
  };

  // prologue: T0 h0, T0 h1, T1 h0 -> fence completes T0 fully, carry = h0(T1)
  stageA(0, 0, 0); stageB(0, 0, 0);
  stageA(0, 1, 0); stageB(0, 1, 0);
  stageA(1, 0, 1); stageB(1, 0, 1);
  fence_steady();

  for (int g = 0; g < NT; ++g) {
    const int buf = g & 1;
    barrier_np();                          // #1: all waves fenced; buf data ready
    stageA(g + 1, 1, buf ^ 1);             // h1 of next tile -> other buffer
    stageB(g + 1, 1, buf ^ 1);

    bf16x8 a[2][4], b[2][NI];
#pragma unroll
    for (int mi = 0; mi < 4; ++mi) {
      int row = wave_m * 64 + mi * 16 + l16;
      const char* rp = lds + buf * BSTRIDE + row * 128;
      int sw = swz(row);
      a[0][mi] = ds_read128(rp + ((quad * 16) ^ sw));
      a[1][mi] = ds_read128(rp + ((64 + quad * 16) ^ sw));
    }
#pragma unroll
    for (int ni = 0; ni < NI; ++ni) {
      int row = wave_n * (BN / 2) + ni * 16 + l16;
      const char* rp = lds + buf * BSTRIDE + 16384 + row * 128;
      int sw = swz(row);
      b[0][ni] = ds_read128(rp + ((quad * 16) ^ sw));
      b[1][ni] = ds_read128(rp + ((64 + quad * 16) ^ sw));
    }
    WAITL0;                                // my reads done
    barrier_np();                          // #2: everyone's reads done
    stageA(g + 2, 0, buf);                 // overwrite h0 of current buf
    stageB(g + 2, 0, buf);

    __builtin_amdgcn_s_setprio(1);
#pragma unroll
    for (int ks = 0; ks < 2; ++ks)
#pragma unroll
      for (int mi = 0; mi < 4; ++mi)
#pragma unroll
        for (int ni = 0; ni < NI; ++ni)
          acc[mi][ni] = __builtin_amdgcn_mfma_f32_16x16x32_bf16(
              a[ks][mi], b[ks][ni], acc[mi][ni], 0, 0, 0);
    __builtin_amdgcn_s_setprio(0);

    if (g + 2 < NT) fence_steady();
    else            asm volatile("s_waitcnt vmcnt(0)" ::: "memory");
  }

  // epilogue: C write (C/D layout: col=l16, row=quad*4+r per 16x16 frag)
#pragma unroll
  for (int mi = 0; mi < 4; ++mi)
#pragma unroll
    for (int ni = 0; ni < NI; ++ni)
#pragma unroll
      for (int r = 0; r < 4; ++r) {
        long row = row0 + wave_m * 64 + mi * 16 + quad * 4 + r;
        long col = col0 + wave_n * (BN / 2) + ni * 16 + l16;
        float v = acc[mi][ni][r];
        if (CMODE == 1) ((unsigned short*)Cout)[row * N + col] = f2b(v);
        else            ((float*)Cout)[row * N + col] = v;
      }
}

// ------------------------------------------- RoPE + sym int8 quant-dequant + split
// qkv[2048][6144] bf16 -> Qb[32][2048][128], Kb[8][2048][128], Vb[8][2048][128]
__global__ __launch_bounds__(256) void postproc(const unsigned short* __restrict__ qkv,
                                                const int* __restrict__ pos_ids,
                                                unsigned short* __restrict__ Qb,
                                                unsigned short* __restrict__ Kb,
                                                unsigned short* __restrict__ Vb) {
  const int s = blockIdx.x;
  const int lane = threadIdx.x & 63, wave = threadIdx.x >> 6;
  const float pos = (float)pos_ids[s];
  // inv_freq = 10000^(-lane/64) = exp(-lane * ln(10000)/64); pair (d, d+64)
  const float invf = expf(-(float)lane * 0.14391156831212787f);
  const float ang = pos * invf;
  const float ca = cosf(ang), sa = sinf(ang);

  for (int r = wave; r < 48; r += 4) {
    if (r < 32) {                 // Q head r: rope only
      const unsigned short* src = qkv + (long)s * QKV_N + r * HD;
      float x0 = b2f(src[lane]), x1 = b2f(src[lane + 64]);
      unsigned short* dst = Qb + ((long)r * S_LEN + s) * HD;
      dst[lane]      = f2b(x0 * ca - x1 * sa);
      dst[lane + 64] = f2b(x1 * ca + x0 * sa);
    } else if (r < 40) {          // K head r-32: rope then quant-dequant
      int h = r - 32;
      const unsigned short* src = qkv + (long)s * QKV_N + 4096 + h * HD;
      float x0 = b2f(src[lane]), x1 = b2f(src[lane + 64]);
      float y0 = x0 * ca - x1 * sa;
      float y1 = x1 * ca + x0 * sa;
      float m = fmaxf(fabsf(y0), fabsf(y1));
      for (int off = 32; off; off >>= 1) m = fmaxf(m, __shfl_xor(m, off, 64));
      float scale = fmaxf(m / 127.0f, 1e-9f);
      float q0 = fminf(fmaxf(rintf(y0 / scale), -128.f), 127.f);
      float q1 = fminf(fmaxf(rintf(y1 / scale), -128.f), 127.f);
      unsigned short* dst = Kb + ((long)h * S_LEN + s) * HD;
      dst[lane]      = f2b(q0 * scale);
      dst[lane + 64] = f2b(q1 * scale);
    } else {                      // V head r-40: quant-dequant only
      int h = r - 40;
      const unsigned short* src = qkv + (long)s * QKV_N + 5120 + h * HD;
      float x0 = b2f(src[lane]), x1 = b2f(src[lane + 64]);
      float m = fmaxf(fabsf(x0), fabsf(x1));
      for (int off = 32; off; off >>= 1) m = fmaxf(m, __shfl_xor(m, off, 64));
      float scale = fmaxf(m / 127.0f, 1e-9f);
      float q0 = fminf(fmaxf(rintf(x0 / scale), -128.f), 127.f);
      float q1 = fminf(fmaxf(rintf(x1 / scale), -128.f), 127.f);
      unsigned short* dst = Vb + ((long)h * S_LEN + s) * HD;
      dst[lane]      = f2b(q0 * scale);
      dst[lane + 64] = f2b(q1 * scale);
    }
  }
}

// -------------------------------------------------- V transpose: [h][s][d]->[h][d][s]
__global__ __launch_bounds__(256) void transpose_v(const unsigned short* __restrict__ Vb,
                                                   unsigned short* __restrict__ Vtb) {
  __shared__ unsigned short t[64][136];
  const int h = blockIdx.x >> 5, st = blockIdx.x & 31;
  const int tid = threadIdx.x;
  const long vbase = (long)h * S_LEN * HD;
#pragma unroll
  for (int p = 0; p < 8; ++p) {
    int e = p * 1024 + tid * 4;
    int sl = e >> 7, d = e & 127;
    ushort4 v = *(const ushort4*)(Vb + vbase + (long)(st * 64 + sl) * HD + d);
    t[sl][d] = v.x; t[sl][d + 1] = v.y; t[sl][d + 2] = v.z; t[sl][d + 3] = v.w;
  }
  __syncthreads();
  const long tbase = (long)h * HD * S_LEN;
#pragma unroll
  for (int p = 0; p < 8; ++p) {
    int o = p * 1024 + tid * 4;
    int d = o >> 6, sl = o & 63;
    ushort4 v;
    v.x = t[sl][d]; v.y = t[sl + 1][d]; v.z = t[sl + 2][d]; v.w = t[sl + 3][d];
    *(ushort4*)(Vtb + tbase + (long)d * S_LEN + st * 64 + sl) = v;
  }
}

// ------------------------------------------------------------- flash attention
// Block = (head, 128-row q-tile), 4 waves x 32 q-rows. KVBLK=64.
// R9: single-buffered K/V (LDS 48KB: K 16K @0, Vt 16K @16384, Ps 16K @32768).
// launch_bounds(256,2): no VGPR cap spill; natural alloc <=170 -> 3 blocks/CU.
// T14 reg-prefetch of tile t+1 issued BETWEEN QK^T and softmax (peak-pressure
// window avoided); vmcnt(0)+ds_write after the post-PV barrier.
// Defer-max (T13, THR=8). Both-sides XOR swizzle on K/Vt/Ps.
__global__ __launch_bounds__(256, 2) void attn_kernel(const unsigned short* __restrict__ Qb,
                                                      const unsigned short* __restrict__ Kb,
                                                      const unsigned short* __restrict__ Vtb,
                                                      unsigned short* __restrict__ Ob) {
  __shared__ __align__(16) char lds[49152];

  const int bx = blockIdx.x;
  const int p8 = bx & 1;
  const int g = (bx >> 1) & 7;
  const int b8 = bx >> 8;
  const int qt = (p8 ^ b8) ? (15 - g) : g;
  const int h = ((bx >> 4) & 15) + 16 * b8;
  const int hk = h >> 2;                        // GQA: 4 q-heads per kv-head
  const int tid = threadIdx.x;
  const int lane = tid & 63, wave = tid >> 6;
  const int quad = lane >> 4, l16 = lane & 15;

  // Q fragments for this wave's 32 rows (A-operand layout), from global
  bf16x8 qf[2][4];
  {
    const unsigned short* qb =
        Qb + ((long)h * S_LEN + qt * 128 + wave * 32 + l16) * HD + quad * 8;
#pragma unroll
    for (int mi = 0; mi < 2; ++mi)
#pragma unroll
      for (int ks = 0; ks < 4; ++ks)
        qf[mi][ks] = *(const bf16x8*)(qb + mi * 16 * HD + ks * 32);
  }

  f32x4 O[2][8] = {};
  float mrow[2][4], lrow[2][4];
#pragma unroll
  for (int mi = 0; mi < 2; ++mi)
#pragma unroll
    for (int r = 0; r < 4; ++r) { mrow[mi][r] = -1e30f; lrow[mi][r] = 0.f; }

  const char* Kg = (const char*)(Kb + (long)hk * S_LEN * HD);
  const char* Vg = (const char*)(Vtb + (long)hk * HD * S_LEN);
  char* PsB = lds + 32768;
  const float sscale = 0.08838834764831845f;  // 1/sqrt(128)
  const int nsteps = 2 * qt + 2;              // 64-key steps

  // T14 prefetch regs: 4x16B K + 4x16B V per thread (same pre-swizzled
  // global addresses and LDS image as gl_lds16 staging would produce).
  int4 kpf[4], vpf[4];
  auto loadRegs = [&](int step) {
    const char* ks = Kg + (long)step * 16384;
    const char* vs = Vg + (long)step * 128;
#pragma unroll
    for (int c = 0; c < 4; ++c) {
      int f = c * 4096 + tid * 16;
      int kr = f >> 8, kb = f & 255;
      kpf[c] = *(const int4*)(ks + kr * 256 + (kb ^ swz(kr)));
      int d = f >> 7, vb = f & 127;
      vpf[c] = *(const int4*)(vs + (long)d * (S_LEN * 2) + (vb ^ swz(d)));
    }
  };
  auto writeLDS = [&]() {
#pragma unroll
    for (int c = 0; c < 4; ++c) {
      *(int4*)(lds + c * 4096 + tid * 16) = kpf[c];
      *(int4*)(lds + 16384 + c * 4096 + tid * 16) = vpf[c];
    }
  };

  // prologue: tile 0 -> regs -> LDS
  loadRegs(0);
  asm volatile("s_waitcnt vmcnt(0)" ::: "memory");
  writeLDS();
  asm volatile("s_waitcnt lgkmcnt(0)" ::: "memory");

  for (int t = 0; t < nsteps; ++t) {
    barrier_np();                       // all waves' tile-t writes visible
    const char* Ks = lds;
    const char* Vs = lds + 16384;

    // ---- S = Q K^T over 64 keys (4 ni of 16)
    f32x4 S[2][4] = {};
    __builtin_amdgcn_s_setprio(1);
#pragma unroll
    for (int ni = 0; ni < 4; ++ni) {
      const int row = ni * 16 + l16;
      const char* kr = Ks + row * 256;
      const int sw = swz(row);
      const int q16 = quad * 16;
      bf16x8 kf0 = *(const bf16x8*)(kr + ((q16 + 0)   ^ sw));
      bf16x8 kf1 = *(const bf16x8*)(kr + ((q16 + 64)  ^ sw));
      bf16x8 kf2 = *(const bf16x8*)(kr + ((q16 + 128) ^ sw));
      bf16x8 kf3 = *(const bf16x8*)(kr + ((q16 + 192) ^ sw));
      S[0][ni] = __builtin_amdgcn_mfma_f32_16x16x32_bf16(qf[0][0], kf0, S[0][ni], 0, 0, 0);
      S[1][ni] = __builtin_amdgcn_mfma_f32_16x16x32_bf16(qf[1][0], kf0, S[1][ni], 0, 0, 0);
      S[0][ni] = __builtin_amdgcn_mfma_f32_16x16x32_bf16(qf[0][1], kf1, S[0][ni], 0, 0, 0);
      S[1][ni] = __builtin_amdgcn_mfma_f32_16x16x32_bf16(qf[1][1], kf1, S[1][ni], 0, 0, 0);
      S[0][ni] = __builtin_amdgcn_mfma_f32_16x16x32_bf16(qf[0][2], kf2, S[0][ni], 0, 0, 0);
      S[1][ni] = __builtin_amdgcn_mfma_f32_16x16x32_bf16(qf[1][2], kf2, S[1][ni], 0, 0, 0);
      S[0][ni] = __builtin_amdgcn_mfma_f32_16x16x32_bf16(qf[0][3], kf3, S[0][ni], 0, 0, 0);
      S[1][ni] = __builtin_amdgcn_mfma_f32_16x16x32_bf16(qf[1][3], kf3, S[1][ni], 0, 0, 0);
    }
    __builtin_amdgcn_s_setprio(0);

    // ---- T14: issue tile t+1 prefetch now (overlaps softmax + PV; avoids
    //      the QK^T peak-register window)
    if (t + 1 < nsteps) {
      loadRegs(t + 1);
      __builtin_amdgcn_sched_barrier(0);
    }

    // ---- scale + causal mask + row max
    const bool diag = (t >= 2 * qt);
    const int qrow_base = qt * 128 + wave * 32;
    float rmax[2][4];
#pragma unroll
    for (int mi = 0; mi < 2; ++mi)
#pragma unroll
      for (int r = 0; r < 4; ++r) rmax[mi][r] = -1e30f;
#pragma unroll
    for (int mi = 0; mi < 2; ++mi)
#pragma unroll
      for (int ni = 0; ni < 4; ++ni) {
        int col = t * 64 + ni * 16 + l16;
#pragma unroll
        for (int r = 0; r < 4; ++r) {
          int row = qrow_base + mi * 16 + quad * 4 + r;
          float v = S[mi][ni][r] * sscale;
          if (diag && col > row) v = -1e9f;
          S[mi][ni][r] = v;
          rmax[mi][r] = fmaxf(rmax[mi][r], v);
        }
      }

    // ---- defer-max (T13): rescale only when some row grew past mrow+8
    bool need = false;
    float pmax[2][4];
#pragma unroll
    for (int mi = 0; mi < 2; ++mi)
#pragma unroll
      for (int r = 0; r < 4; ++r) {
        float v = rmax[mi][r];
        v = fmaxf(v, __shfl_xor(v, 1, 64));
        v = fmaxf(v, __shfl_xor(v, 2, 64));
        v = fmaxf(v, __shfl_xor(v, 4, 64));
        v = fmaxf(v, __shfl_xor(v, 8, 64));
        pmax[mi][r] = v;
        need = need || (v > mrow[mi][r] + 8.0f);
      }
    if (__any(need)) {
      float alpha[2][4];
#pragma unroll
      for (int mi = 0; mi < 2; ++mi)
#pragma unroll
        for (int r = 0; r < 4; ++r) {
          float mnew = fmaxf(mrow[mi][r], pmax[mi][r]);
          alpha[mi][r] = __expf(mrow[mi][r] - mnew);
          mrow[mi][r] = mnew;
          lrow[mi][r] *= alpha[mi][r];
        }
#pragma unroll
      for (int mi = 0; mi < 2; ++mi)
#pragma unroll
        for (int ni = 0; ni < 8; ++ni)
#pragma unroll
          for (int r = 0; r < 4; ++r) O[mi][ni][r] *= alpha[mi][r];
    }

    // ---- P = exp(S - m) -> wave-local swizzled LDS rows, accumulate sums
    float rsum[2][4] = {};
#pragma unroll
    for (int mi = 0; mi < 2; ++mi)
#pragma unroll
      for (int ni = 0; ni < 4; ++ni)
#pragma unroll
        for (int r = 0; r < 4; ++r) {
          float p = __expf(S[mi][ni][r] - mrow[mi][r]);
          rsum[mi][r] += p;
          int prow = wave * 32 + mi * 16 + quad * 4 + r;
          int pcol2 = (ni * 16 + l16) * 2;
          *(unsigned short*)(PsB + prow * 128 + (pcol2 ^ swz(prow))) = f2b(p);
        }
#pragma unroll
    for (int mi = 0; mi < 2; ++mi)
#pragma unroll
      for (int r = 0; r < 4; ++r) {
        float v = rsum[mi][r];
        v += __shfl_xor(v, 1, 64);
        v += __shfl_xor(v, 2, 64);
        v += __shfl_xor(v, 4, 64);
        v += __shfl_xor(v, 8, 64);
        lrow[mi][r] += v;
      }

    // ---- O += P V : P A-frags from wave-local LDS, Vt B-frags from LDS tile
    bf16x8 pf[2][2];
#pragma unroll
    for (int mi = 0; mi < 2; ++mi)
#pragma unroll
      for (int ks2 = 0; ks2 < 2; ++ks2) {
        int prow = wave * 32 + mi * 16 + l16;
        pf[mi][ks2] = *(const bf16x8*)(PsB + prow * 128 +
                                       ((ks2 * 64 + quad * 16) ^ swz(prow)));
      }
    __builtin_amdgcn_s_setprio(1);
#pragma unroll
    for (int ni = 0; ni < 8; ++ni) {
      const int row = ni * 16 + l16;
      const char* vr = Vs + row * 128;
      const int sw = swz(row);
      const int q16 = quad * 16;
      bf16x8 vf0 = *(const bf16x8*)(vr + ((q16 + 0)  ^ sw));
      bf16x8 vf1 = *(const bf16x8*)(vr + ((q16 + 64) ^ sw));
      O[0][ni] = __builtin_amdgcn_mfma_f32_16x16x32_bf16(pf[0][0], vf0, O[0][ni], 0, 0, 0);
      O[1][ni] = __builtin_amdgcn_mfma_f32_16x16x32_bf16(pf[1][0], vf0, O[1][ni], 0, 0, 0);
      O[0][ni] = __builtin_amdgcn_mfma_f32_16x16x32_bf16(pf[0][1], vf1, O[0][ni], 0, 0, 0);
      O[1][ni] = __builtin_amdgcn_mfma_f32_16x16x32_bf16(pf[1][1], vf1, O[1][ni], 0, 0, 0);
    }
    __builtin_amdgcn_s_setprio(0);

    barrier_np();                       // all waves done reading tile t
    if (t + 1 < nsteps) {
      asm volatile("s_waitcnt vmcnt(0)" ::: "memory");
      writeLDS();                       // tile t+1 -> LDS
      asm volatile("s_waitcnt lgkmcnt(0)" ::: "memory");
    }
  }

  // normalize + store bf16 at [s][h*128+d]
#pragma unroll
  for (int mi = 0; mi < 2; ++mi)
#pragma unroll
    for (int r = 0; r < 4; ++r) {
      float inv = 1.0f / lrow[mi][r];
      long srow = qt * 128 + wave * 32 + mi * 16 + quad * 4 + r;
#pragma unroll
      for (int ni = 0; ni < 8; ++ni) {
        long col = (long)h * HD + ni * 16 + l16;
        Ob[srow * (long)HID + col] = f2b(O[mi][ni][r] * inv);
      }
    }
}

// ---------------------------------------------------------------------------
extern "C" void kernel_launch(void* const* d_in, const int* in_sizes, int n_in,
                              void* d_out, int out_size, void* d_ws, size_t ws_size,
                              hipStream_t stream) {
  const float* hidden = (const float*)d_in[0];
  const float* wq = (const float*)d_in[1];
  const float* wk = (const float*)d_in[2];
  const float* wv = (const float*)d_in[3];
  const float* wo = (const float*)d_in[4];
  const int* pos = (const int*)d_in[5];
  float* out = (float*)d_out;

  // workspace layout (bytes); total 138,412,032. Overlays: Qb=hid_b (hid dead
  // after GEMM1), attn_b=qkv_b (qkv dead after postproc).
  char* ws = (char*)d_ws;
  unsigned short* wqkv_b = (unsigned short*)(ws);               // 50,331,648
  unsigned short* wo_b   = (unsigned short*)(ws + 50331648);    // 33,554,432
  unsigned short* hid_b  = (unsigned short*)(ws + 83886080);    // 16,777,216
  unsigned short* qkv_b  = (unsigned short*)(ws + 100663296);   // 25,165,824
  unsigned short* Kb     = (unsigned short*)(ws + 125829120);   //  4,194,304
  unsigned short* Vb     = (unsigned short*)(ws + 130023424);   //  4,194,304
  unsigned short* Vtb    = (unsigned short*)(ws + 134217728);   //  4,194,304
  unsigned short* Qb     = hid_b;
  unsigned short* attn_b = qkv_b;

  cast_kernel<<<8388608 / 1024, 256, 0, stream>>>(hidden, hid_b, 8388608 / 4);
  cast_kernel<<<16777216 / 1024, 256, 0, stream>>>(wq, wqkv_b, 16777216 / 4);
  cast_kernel<<<4194304 / 1024, 256, 0, stream>>>(wk, wqkv_b + 16777216, 4194304 / 4);
  cast_kernel<<<4194304 / 1024, 256, 0, stream>>>(wv, wqkv_b + 20971520, 4194304 / 4);
  cast_kernel<<<16777216 / 1024, 256, 0, stream>>>(wo, wo_b, 16777216 / 4);

  // QKV: 128x192 tiles -> grid 32x16 = 512 blocks = 2/CU, 100% fill
  gemm_bt<192, 1><<<dim3(QKV_N / 192, S_LEN / 128), 256, 0, stream>>>(
      hid_b, wqkv_b, (void*)qkv_b, S_LEN, QKV_N, HID);

  postproc<<<S_LEN, 256, 0, stream>>>(qkv_b, pos, Qb, Kb, Vb);
  transpose_v<<<NKV * 32, 256, 0, stream>>>(Vb, Vtb);
  attn_kernel<<<NH * 16, 256, 0, stream>>>(Qb, Kb, Vtb, attn_b);

  // out-proj: 128x128 tiles -> grid 32x16 = 512 blocks = 2/CU, 100% fill
  gemm_bt<128, 0><<<dim3(HID / 128, S_LEN / 128), 256, 0, stream>>>(
      attn_b, wo_b, (void*)out, S_LEN, HID, HID);
}

// Round 8
// 498.752 us; speedup vs baseline: 1.6026x; 1.0876x over previous
//
#include <hip/hip_runtime.h>

// ---------------------------------------------------------------------------
// LlamaAttention_Tender: hidden(2048x4096) -> QKV proj -> RoPE -> int8 qdq(K,V)
// -> GQA causal attention (32 q-heads, 8 kv-heads, D=128) -> out proj.
// R10: re-anchor at R7 (best verified: 489.6us). Attention reverted to the
//      proven R7 structure (double-buffered global_load_lds staging, 80KB
//      LDS, __syncthreads drain) + ONE additive low-risk change: T13
//      defer-max (THR=8) — skip alpha/O-rescale/lrow-rescale unless
//      __any(rowmax > mrow+8); P bounded by e^8, f32 accum headroom.
//      R8/R9 post-mortem: reg-staged single-buffer attn spills (allocator
//      keeps prefetch regs in scratch at <=128 VGPR target) — abandoned.
//      GEMMs unchanged from R7 (128xBN, 2 blocks/CU, full fill).
// ---------------------------------------------------------------------------

#define S_LEN 2048
#define HID 4096
#define NH 32
#define NKV 8
#define HD 128
#define QKV_N 6144   // 4096 q + 1024 k + 1024 v

typedef __bf16 bf16x8 __attribute__((ext_vector_type(8)));
typedef float f32x4 __attribute__((ext_vector_type(4)));

__device__ __forceinline__ unsigned short f2b(float f) {
  unsigned int u = __float_as_uint(f);
  u += 0x7fffu + ((u >> 16) & 1u);   // round-to-nearest-even
  return (unsigned short)(u >> 16);
}
__device__ __forceinline__ float b2f(unsigned short h) {
  return __uint_as_float(((unsigned int)h) << 16);
}
// async global->LDS, 16B per lane. LDS dst must be wave-uniform (lane*16 implicit).
__device__ __forceinline__ void gl_lds16(const void* g, void* l) {
  __builtin_amdgcn_global_load_lds(
      (__attribute__((address_space(1))) void*)g,
      (__attribute__((address_space(3))) void*)l, 16, 0, 0);
}
// compiler-opaque LDS b128 read (no alias info -> no auto vmcnt drains).
__device__ __forceinline__ bf16x8 ds_read128(const void* p) {
  bf16x8 r;
  unsigned a = (unsigned)(unsigned long long)
      (__attribute__((address_space(3))) const void*)p;
  asm volatile("ds_read_b128 %0, %1" : "=v"(r) : "v"(a));
  return r;
}
// LDS bank-spread swizzle: permutes 16B chunks within a 128B row; involution.
__device__ __forceinline__ int swz(int row) {
  return ((row & 7) << 4) ^ (((row >> 3) & 1) << 5);
}
// barrier without the __syncthreads vmcnt(0) drain; asm fences stop IR motion
__device__ __forceinline__ void barrier_np() {
  asm volatile("" ::: "memory");
  __builtin_amdgcn_s_barrier();
  asm volatile("" ::: "memory");
}
#define WAITL0                                            \
  do {                                                    \
    asm volatile("s_waitcnt lgkmcnt(0)" ::: "memory");    \
    __builtin_amdgcn_sched_barrier(0);                    \
  } while (0)

// ---------------------------------------------------------------- cast fp32->bf16
__global__ __launch_bounds__(256) void cast_kernel(const float* __restrict__ src,
                                                   unsigned short* __restrict__ dst,
                                                   int n4) {
  int i = blockIdx.x * 256 + threadIdx.x;
  if (i >= n4) return;
  float4 v = ((const float4*)src)[i];
  ushort4 o;
  o.x = f2b(v.x); o.y = f2b(v.y); o.z = f2b(v.z); o.w = f2b(v.w);
  ((ushort4*)dst)[i] = o;
}

// --------------------------------- B^T GEMM, 128xBN tile, 4 waves, 2 blocks/CU
// C[M,N] = A[M,K]*B[N,K]^T. 256 thr = 4 waves (2Mx2N), per-wave out 64x(BN/2).
// LDS per buffer: A 16KB + B BN*128B; double-buffered. BK=64, NT=K/64.
// CMODE: 0 = f32 store, 1 = bf16 store.
template <int BN, int CMODE>
__global__ __launch_bounds__(256, 2) void gemm_bt(const unsigned short* __restrict__ A,
                                                  const unsigned short* __restrict__ B,
                                                  void* __restrict__ Cout,
                                                  int M, int N, int K) {
  constexpr int NI = BN / 32;                 // per-wave ni count (6 or 4)
  constexpr int BSTRIDE = 16384 + BN * 128;   // per-buffer LDS bytes
  __shared__ __align__(16) char lds[2 * BSTRIDE];
  const int tid = threadIdx.x;
  const int lane = tid & 63, wave = tid >> 6;
  const int quad = lane >> 4, l16 = lane & 15;
  const int wave_m = wave >> 1, wave_n = wave & 1;
  const long row0 = (long)blockIdx.y * 128;
  const long col0 = (long)blockIdx.x * BN;
  const int NT = K >> 6;
  const long rowstride = (long)K * 2;

  f32x4 acc[4][NI] = {};

  // stage A half-tile (64 rows, 8KB): 2 gl_lds per wave
  auto stageA = [&](int T, int h, int buf) {
    if (T >= NT) return;
    char* dst = lds + buf * BSTRIDE + h * 8192 + wave * 1024;
    const char* src = (const char*)A + (row0 + h * 64) * rowstride + (long)T * 128;
#pragma unroll
    for (int c = 0; c < 2; ++c) {
      int b = c * 4096 + wave * 1024 + lane * 16;
      int r = b >> 7, cb = b & 127;
      gl_lds16(src + (long)r * rowstride + (cb ^ swz(r)), dst + c * 4096);
    }
  };
  // stage B half-tile (BN/2 rows): BN/64 gl_lds per wave
  auto stageB = [&](int T, int h, int buf) {
    if (T >= NT) return;
    char* dst = lds + buf * BSTRIDE + 16384 + h * (BN * 64) + wave * 1024;
    const char* src = (const char*)B + (col0 + h * (BN / 2)) * rowstride + (long)T * 128;
#pragma unroll
    for (int c = 0; c < BN / 64; ++c) {
      int b = c * 4096 + wave * 1024 + lane * 16;
      int r = b >> 7, cb = b & 127;
      gl_lds16(src + (long)r * rowstride + (cb ^ swz(r)), dst + c * 4096);
    }
  };
  // counted vmcnt: HOPS = ops per (A-half + B-half) stage pair = 2 + BN/64
  auto fence_steady = [&]() {
    if (BN == 192) asm volatile("s_waitcnt vmcnt(5)" ::: "memory");
    else           asm volatile("s_waitcnt vmcnt(4)" ::: "memory");
  };

  // prologue: T0 h0, T0 h1, T1 h0 -> fence completes T0 fully, carry = h0(T1)
  stageA(0, 0, 0); stageB(0, 0, 0);
  stageA(0, 1, 0); stageB(0, 1, 0);
  stageA(1, 0, 1); stageB(1, 0, 1);
  fence_steady();

  for (int g = 0; g < NT; ++g) {
    const int buf = g & 1;
    barrier_np();                          // #1: all waves fenced; buf data ready
    stageA(g + 1, 1, buf ^ 1);             // h1 of next tile -> other buffer
    stageB(g + 1, 1, buf ^ 1);

    bf16x8 a[2][4], b[2][NI];
#pragma unroll
    for (int mi = 0; mi < 4; ++mi) {
      int row = wave_m * 64 + mi * 16 + l16;
      const char* rp = lds + buf * BSTRIDE + row * 128;
      int sw = swz(row);
      a[0][mi] = ds_read128(rp + ((quad * 16) ^ sw));
      a[1][mi] = ds_read128(rp + ((64 + quad * 16) ^ sw));
    }
#pragma unroll
    for (int ni = 0; ni < NI; ++ni) {
      int row = wave_n * (BN / 2) + ni * 16 + l16;
      const char* rp = lds + buf * BSTRIDE + 16384 + row * 128;
      int sw = swz(row);
      b[0][ni] = ds_read128(rp + ((quad * 16) ^ sw));
      b[1][ni] = ds_read128(rp + ((64 + quad * 16) ^ sw));
    }
    WAITL0;                                // my reads done
    barrier_np();                          // #2: everyone's reads done
    stageA(g + 2, 0, buf);                 // overwrite h0 of current buf
    stageB(g + 2, 0, buf);

    __builtin_amdgcn_s_setprio(1);
#pragma unroll
    for (int ks = 0; ks < 2; ++ks)
#pragma unroll
      for (int mi = 0; mi < 4; ++mi)
#pragma unroll
        for (int ni = 0; ni < NI; ++ni)
          acc[mi][ni] = __builtin_amdgcn_mfma_f32_16x16x32_bf16(
              a[ks][mi], b[ks][ni], acc[mi][ni], 0, 0, 0);
    __builtin_amdgcn_s_setprio(0);

    if (g + 2 < NT) fence_steady();
    else            asm volatile("s_waitcnt vmcnt(0)" ::: "memory");
  }

  // epilogue: C write (C/D layout: col=l16, row=quad*4+r per 16x16 frag)
#pragma unroll
  for (int mi = 0; mi < 4; ++mi)
#pragma unroll
    for (int ni = 0; ni < NI; ++ni)
#pragma unroll
      for (int r = 0; r < 4; ++r) {
        long row = row0 + wave_m * 64 + mi * 16 + quad * 4 + r;
        long col = col0 + wave_n * (BN / 2) + ni * 16 + l16;
        float v = acc[mi][ni][r];
        if (CMODE == 1) ((unsigned short*)Cout)[row * N + col] = f2b(v);
        else            ((float*)Cout)[row * N + col] = v;
      }
}

// ------------------------------------------- RoPE + sym int8 quant-dequant + split
// qkv[2048][6144] bf16 -> Qb[32][2048][128], Kb[8][2048][128], Vb[8][2048][128]
__global__ __launch_bounds__(256) void postproc(const unsigned short* __restrict__ qkv,
                                                const int* __restrict__ pos_ids,
                                                unsigned short* __restrict__ Qb,
                                                unsigned short* __restrict__ Kb,
                                                unsigned short* __restrict__ Vb) {
  const int s = blockIdx.x;
  const int lane = threadIdx.x & 63, wave = threadIdx.x >> 6;
  const float pos = (float)pos_ids[s];
  // inv_freq = 10000^(-lane/64) = exp(-lane * ln(10000)/64); pair (d, d+64)
  const float invf = expf(-(float)lane * 0.14391156831212787f);
  const float ang = pos * invf;
  const float ca = cosf(ang), sa = sinf(ang);

  for (int r = wave; r < 48; r += 4) {
    if (r < 32) {                 // Q head r: rope only
      const unsigned short* src = qkv + (long)s * QKV_N + r * HD;
      float x0 = b2f(src[lane]), x1 = b2f(src[lane + 64]);
      unsigned short* dst = Qb + ((long)r * S_LEN + s) * HD;
      dst[lane]      = f2b(x0 * ca - x1 * sa);
      dst[lane + 64] = f2b(x1 * ca + x0 * sa);
    } else if (r < 40) {          // K head r-32: rope then quant-dequant
      int h = r - 32;
      const unsigned short* src = qkv + (long)s * QKV_N + 4096 + h * HD;
      float x0 = b2f(src[lane]), x1 = b2f(src[lane + 64]);
      float y0 = x0 * ca - x1 * sa;
      float y1 = x1 * ca + x0 * sa;
      float m = fmaxf(fabsf(y0), fabsf(y1));
      for (int off = 32; off; off >>= 1) m = fmaxf(m, __shfl_xor(m, off, 64));
      float scale = fmaxf(m / 127.0f, 1e-9f);
      float q0 = fminf(fmaxf(rintf(y0 / scale), -128.f), 127.f);
      float q1 = fminf(fmaxf(rintf(y1 / scale), -128.f), 127.f);
      unsigned short* dst = Kb + ((long)h * S_LEN + s) * HD;
      dst[lane]      = f2b(q0 * scale);
      dst[lane + 64] = f2b(q1 * scale);
    } else {                      // V head r-40: quant-dequant only
      int h = r - 40;
      const unsigned short* src = qkv + (long)s * QKV_N + 5120 + h * HD;
      float x0 = b2f(src[lane]), x1 = b2f(src[lane + 64]);
      float m = fmaxf(fabsf(x0), fabsf(x1));
      for (int off = 32; off; off >>= 1) m = fmaxf(m, __shfl_xor(m, off, 64));
      float scale = fmaxf(m / 127.0f, 1e-9f);
      float q0 = fminf(fmaxf(rintf(x0 / scale), -128.f), 127.f);
      float q1 = fminf(fmaxf(rintf(x1 / scale), -128.f), 127.f);
      unsigned short* dst = Vb + ((long)h * S_LEN + s) * HD;
      dst[lane]      = f2b(q0 * scale);
      dst[lane + 64] = f2b(q1 * scale);
    }
  }
}

// -------------------------------------------------- V transpose: [h][s][d]->[h][d][s]
__global__ __launch_bounds__(256) void transpose_v(const unsigned short* __restrict__ Vb,
                                                   unsigned short* __restrict__ Vtb) {
  __shared__ unsigned short t[64][136];
  const int h = blockIdx.x >> 5, st = blockIdx.x & 31;
  const int tid = threadIdx.x;
  const long vbase = (long)h * S_LEN * HD;
#pragma unroll
  for (int p = 0; p < 8; ++p) {
    int e = p * 1024 + tid * 4;
    int sl = e >> 7, d = e & 127;
    ushort4 v = *(const ushort4*)(Vb + vbase + (long)(st * 64 + sl) * HD + d);
    t[sl][d] = v.x; t[sl][d + 1] = v.y; t[sl][d + 2] = v.z; t[sl][d + 3] = v.w;
  }
  __syncthreads();
  const long tbase = (long)h * HD * S_LEN;
#pragma unroll
  for (int p = 0; p < 8; ++p) {
    int o = p * 1024 + tid * 4;
    int d = o >> 6, sl = o & 63;
    ushort4 v;
    v.x = t[sl][d]; v.y = t[sl + 1][d]; v.z = t[sl + 2][d]; v.w = t[sl + 3][d];
    *(ushort4*)(Vtb + tbase + (long)d * S_LEN + st * 64 + sl) = v;
  }
}

// ------------------------------------------------------------- flash attention
// Block = (head, 128-row q-tile), 4 waves x 32 q-rows. KVBLK=64.
// R7 structure (proven): K tile [64 keys][128 d] and Vt tile [128 d][64 keys]
// staged in LDS via global_load_lds, double-buffered 2-phase:
//   __syncthreads (drains stage) -> issue stage(t+1) -> compute(t).
// XOR swizzle on K/Vt/Ps applied BOTH sides (pre-swizzled global source,
// swizzled ds_read/ds_write). LDS: K 2x16K + Vt 2x16K + Ps 16K = 80 KB.
// R10 addition: T13 defer-max (THR=8) — rescale only when a row max grows
// past mrow+8; otherwise keep old max (P bounded by e^8, f32 headroom).
__global__ __launch_bounds__(256, 2) void attn_kernel(const unsigned short* __restrict__ Qb,
                                                      const unsigned short* __restrict__ Kb,
                                                      const unsigned short* __restrict__ Vtb,
                                                      unsigned short* __restrict__ Ob) {
  __shared__ __align__(16) char lds[81920];
  // layout: K buf0 @0, K buf1 @16384, V buf0 @32768, V buf1 @49152, Ps @65536

  const int bx = blockIdx.x;
  const int p8 = bx & 1;
  const int g = (bx >> 1) & 7;
  const int b8 = bx >> 8;
  const int qt = (p8 ^ b8) ? (15 - g) : g;
  const int h = ((bx >> 4) & 15) + 16 * b8;
  const int hk = h >> 2;                        // GQA: 4 q-heads per kv-head
  const int tid = threadIdx.x;
  const int lane = tid & 63, wave = tid >> 6;
  const int quad = lane >> 4, l16 = lane & 15;

  // Q fragments for this wave's 32 rows (A-operand layout), from global
  bf16x8 qf[2][4];
  {
    const unsigned short* qb =
        Qb + ((long)h * S_LEN + qt * 128 + wave * 32 + l16) * HD + quad * 8;
#pragma unroll
    for (int mi = 0; mi < 2; ++mi)
#pragma unroll
      for (int ks = 0; ks < 4; ++ks)
        qf[mi][ks] = *(const bf16x8*)(qb + mi * 16 * HD + ks * 32);
  }

  f32x4 O[2][8] = {};
  float mrow[2][4], lrow[2][4];
#pragma unroll
  for (int mi = 0; mi < 2; ++mi)
#pragma unroll
    for (int r = 0; r < 4; ++r) { mrow[mi][r] = -1e30f; lrow[mi][r] = 0.f; }

  const char* Kg = (const char*)(Kb + (long)hk * S_LEN * HD);
  const char* Vg = (const char*)(Vtb + (long)hk * HD * S_LEN);
  char* PsB = lds + 65536;
  const float sscale = 0.08838834764831845f;  // 1/sqrt(128)
  const int nsteps = 2 * qt + 2;              // 64-key steps

  // stage one 64-key K tile (16 KB, contiguous rows in global) into buf
  auto stageK = [&](int step, int buf) {
    char* dst = lds + buf * 16384 + wave * 1024;
    const char* src = Kg + (long)step * 16384;
#pragma unroll
    for (int c = 0; c < 4; ++c) {
      int f = c * 4096 + tid * 16;
      int row = f >> 8, wb = f & 255;
      gl_lds16(src + row * 256 + (wb ^ swz(row)), dst + c * 4096);
    }
  };
  // stage one Vt tile [128 d][64 keys] (d-rows strided 4096B in global)
  auto stageV = [&](int step, int buf) {
    char* dst = lds + 32768 + buf * 16384 + wave * 1024;
    const char* src = Vg + (long)step * 128;
#pragma unroll
    for (int c = 0; c < 4; ++c) {
      int f = c * 4096 + tid * 16;
      int d = f >> 7, wb = f & 127;
      gl_lds16(src + (long)d * (S_LEN * 2) + (wb ^ swz(d)), dst + c * 4096);
    }
  };

  stageK(0, 0);
  stageV(0, 0);

  for (int t = 0; t < nsteps; ++t) {
    __syncthreads();   // drains this wave's stage (vmcnt 0) + syncs all waves
    if (t + 1 < nsteps) {
      stageK(t + 1, (t + 1) & 1);
      stageV(t + 1, (t + 1) & 1);
    }
    const char* Ks = lds + (t & 1) * 16384;
    const char* Vs = lds + 32768 + (t & 1) * 16384;

    // ---- S = Q K^T over 64 keys (4 ni of 16)
    f32x4 S[2][4] = {};
    __builtin_amdgcn_s_setprio(1);
#pragma unroll
    for (int ni = 0; ni < 4; ++ni) {
      const int row = ni * 16 + l16;
      const char* kr = Ks + row * 256;
      const int sw = swz(row);
      const int q16 = quad * 16;
      bf16x8 kf0 = *(const bf16x8*)(kr + ((q16 + 0)   ^ sw));
      bf16x8 kf1 = *(const bf16x8*)(kr + ((q16 + 64)  ^ sw));
      bf16x8 kf2 = *(const bf16x8*)(kr + ((q16 + 128) ^ sw));
      bf16x8 kf3 = *(const bf16x8*)(kr + ((q16 + 192) ^ sw));
      S[0][ni] = __builtin_amdgcn_mfma_f32_16x16x32_bf16(qf[0][0], kf0, S[0][ni], 0, 0, 0);
      S[1][ni] = __builtin_amdgcn_mfma_f32_16x16x32_bf16(qf[1][0], kf0, S[1][ni], 0, 0, 0);
      S[0][ni] = __builtin_amdgcn_mfma_f32_16x16x32_bf16(qf[0][1], kf1, S[0][ni], 0, 0, 0);
      S[1][ni] = __builtin_amdgcn_mfma_f32_16x16x32_bf16(qf[1][1], kf1, S[1][ni], 0, 0, 0);
      S[0][ni] = __builtin_amdgcn_mfma_f32_16x16x32_bf16(qf[0][2], kf2, S[0][ni], 0, 0, 0);
      S[1][ni] = __builtin_amdgcn_mfma_f32_16x16x32_bf16(qf[1][2], kf2, S[1][ni], 0, 0, 0);
      S[0][ni] = __builtin_amdgcn_mfma_f32_16x16x32_bf16(qf[0][3], kf3, S[0][ni], 0, 0, 0);
      S[1][ni] = __builtin_amdgcn_mfma_f32_16x16x32_bf16(qf[1][3], kf3, S[1][ni], 0, 0, 0);
    }
    __builtin_amdgcn_s_setprio(0);

    // ---- scale + causal mask + row max
    const bool diag = (t >= 2 * qt);
    const int qrow_base = qt * 128 + wave * 32;
    float rmax[2][4];
#pragma unroll
    for (int mi = 0; mi < 2; ++mi)
#pragma unroll
      for (int r = 0; r < 4; ++r) rmax[mi][r] = -1e30f;
#pragma unroll
    for (int mi = 0; mi < 2; ++mi)
#pragma unroll
      for (int ni = 0; ni < 4; ++ni) {
        int col = t * 64 + ni * 16 + l16;
#pragma unroll
        for (int r = 0; r < 4; ++r) {
          int row = qrow_base + mi * 16 + quad * 4 + r;
          float v = S[mi][ni][r] * sscale;
          if (diag && col > row) v = -1e9f;
          S[mi][ni][r] = v;
          rmax[mi][r] = fmaxf(rmax[mi][r], v);
        }
      }

    // ---- T13 defer-max: rescale only when some row grew past mrow+8
    bool need = false;
    float pmax[2][4];
#pragma unroll
    for (int mi = 0; mi < 2; ++mi)
#pragma unroll
      for (int r = 0; r < 4; ++r) {
        float v = rmax[mi][r];
        v = fmaxf(v, __shfl_xor(v, 1, 64));
        v = fmaxf(v, __shfl_xor(v, 2, 64));
        v = fmaxf(v, __shfl_xor(v, 4, 64));
        v = fmaxf(v, __shfl_xor(v, 8, 64));
        pmax[mi][r] = v;
        need = need || (v > mrow[mi][r] + 8.0f);
      }
    if (__any(need)) {
      float alpha[2][4];
#pragma unroll
      for (int mi = 0; mi < 2; ++mi)
#pragma unroll
        for (int r = 0; r < 4; ++r) {
          float mnew = fmaxf(mrow[mi][r], pmax[mi][r]);
          alpha[mi][r] = __expf(mrow[mi][r] - mnew);
          mrow[mi][r] = mnew;
          lrow[mi][r] *= alpha[mi][r];
        }
#pragma unroll
      for (int mi = 0; mi < 2; ++mi)
#pragma unroll
        for (int ni = 0; ni < 8; ++ni)
#pragma unroll
          for (int r = 0; r < 4; ++r) O[mi][ni][r] *= alpha[mi][r];
    }

    // ---- P = exp(S - m) -> wave-local swizzled LDS rows, accumulate sums
    float rsum[2][4] = {};
#pragma unroll
    for (int mi = 0; mi < 2; ++mi)
#pragma unroll
      for (int ni = 0; ni < 4; ++ni)
#pragma unroll
        for (int r = 0; r < 4; ++r) {
          float p = __expf(S[mi][ni][r] - mrow[mi][r]);
          rsum[mi][r] += p;
          int prow = wave * 32 + mi * 16 + quad * 4 + r;
          int pcol2 = (ni * 16 + l16) * 2;
          *(unsigned short*)(PsB + prow * 128 + (pcol2 ^ swz(prow))) = f2b(p);
        }
#pragma unroll
    for (int mi = 0; mi < 2; ++mi)
#pragma unroll
      for (int r = 0; r < 4; ++r) {
        float v = rsum[mi][r];
        v += __shfl_xor(v, 1, 64);
        v += __shfl_xor(v, 2, 64);
        v += __shfl_xor(v, 4, 64);
        v += __shfl_xor(v, 8, 64);
        lrow[mi][r] += v;
      }

    // ---- O += P V : P A-frags from wave-local LDS, Vt B-frags from LDS tile
    bf16x8 pf[2][2];
#pragma unroll
    for (int mi = 0; mi < 2; ++mi)
#pragma unroll
      for (int ks2 = 0; ks2 < 2; ++ks2) {
        int prow = wave * 32 + mi * 16 + l16;
        pf[mi][ks2] = *(const bf16x8*)(PsB + prow * 128 +
                                       ((ks2 * 64 + quad * 16) ^ swz(prow)));
      }
    __builtin_amdgcn_s_setprio(1);
#pragma unroll
    for (int ni = 0; ni < 8; ++ni) {
      const int row = ni * 16 + l16;
      const char* vr = Vs + row * 128;
      const int sw = swz(row);
      const int q16 = quad * 16;
      bf16x8 vf0 = *(const bf16x8*)(vr + ((q16 + 0)  ^ sw));
      bf16x8 vf1 = *(const bf16x8*)(vr + ((q16 + 64) ^ sw));
      O[0][ni] = __builtin_amdgcn_mfma_f32_16x16x32_bf16(pf[0][0], vf0, O[0][ni], 0, 0, 0);
      O[1][ni] = __builtin_amdgcn_mfma_f32_16x16x32_bf16(pf[1][0], vf0, O[1][ni], 0, 0, 0);
      O[0][ni] = __builtin_amdgcn_mfma_f32_16x16x32_bf16(pf[0][1], vf1, O[0][ni], 0, 0, 0);
      O[1][ni] = __builtin_amdgcn_mfma_f32_16x16x32_bf16(pf[1][1], vf1, O[1][ni], 0, 0, 0);
    }
    __builtin_amdgcn_s_setprio(0);
  }

  // normalize + store bf16 at [s][h*128+d]
#pragma unroll
  for (int mi = 0; mi < 2; ++mi)
#pragma unroll
    for (int r = 0; r < 4; ++r) {
      float inv = 1.0f / lrow[mi][r];
      long srow = qt * 128 + wave * 32 + mi * 16 + quad * 4 + r;
#pragma unroll
      for (int ni = 0; ni < 8; ++ni) {
        long col = (long)h * HD + ni * 16 + l16;
        Ob[srow * (long)HID + col] = f2b(O[mi][ni][r] * inv);
      }
    }
}

// ---------------------------------------------------------------------------
extern "C" void kernel_launch(void* const* d_in, const int* in_sizes, int n_in,
                              void* d_out, int out_size, void* d_ws, size_t ws_size,
                              hipStream_t stream) {
  const float* hidden = (const float*)d_in[0];
  const float* wq = (const float*)d_in[1];
  const float* wk = (const float*)d_in[2];
  const float* wv = (const float*)d_in[3];
  const float* wo = (const float*)d_in[4];
  const int* pos = (const int*)d_in[5];
  float* out = (float*)d_out;

  // workspace layout (bytes); total 138,412,032. Overlays: Qb=hid_b (hid dead
  // after GEMM1), attn_b=qkv_b (qkv dead after postproc).
  char* ws = (char*)d_ws;
  unsigned short* wqkv_b = (unsigned short*)(ws);               // 50,331,648
  unsigned short* wo_b   = (unsigned short*)(ws + 50331648);    // 33,554,432
  unsigned short* hid_b  = (unsigned short*)(ws + 83886080);    // 16,777,216
  unsigned short* qkv_b  = (unsigned short*)(ws + 100663296);   // 25,165,824
  unsigned short* Kb     = (unsigned short*)(ws + 125829120);   //  4,194,304
  unsigned short* Vb     = (unsigned short*)(ws + 130023424);   //  4,194,304
  unsigned short* Vtb    = (unsigned short*)(ws + 134217728);   //  4,194,304
  unsigned short* Qb     = hid_b;
  unsigned short* attn_b = qkv_b;

  cast_kernel<<<8388608 / 1024, 256, 0, stream>>>(hidden, hid_b, 8388608 / 4);
  cast_kernel<<<16777216 / 1024, 256, 0, stream>>>(wq, wqkv_b, 16777216 / 4);
  cast_kernel<<<4194304 / 1024, 256, 0, stream>>>(wk, wqkv_b + 16777216, 4194304 / 4);
  cast_kernel<<<4194304 / 1024, 256, 0, stream>>>(wv, wqkv_b + 20971520, 4194304 / 4);
  cast_kernel<<<16777216 / 1024, 256, 0, stream>>>(wo, wo_b, 16777216 / 4);

  // QKV: 128x192 tiles -> grid 32x16 = 512 blocks = 2/CU, 100% fill
  gemm_bt<192, 1><<<dim3(QKV_N / 192, S_LEN / 128), 256, 0, stream>>>(
      hid_b, wqkv_b, (void*)qkv_b, S_LEN, QKV_N, HID);

  postproc<<<S_LEN, 256, 0, stream>>>(qkv_b, pos, Qb, Kb, Vb);
  transpose_v<<<NKV * 32, 256, 0, stream>>>(Vb, Vtb);
  attn_kernel<<<NH * 16, 256, 0, stream>>>(Qb, Kb, Vtb, attn_b);

  // out-proj: 128x128 tiles -> grid 32x16 = 512 blocks = 2/CU, 100% fill
  gemm_bt<128, 0><<<dim3(HID / 128, S_LEN / 128), 256, 0, stream>>>(
      attn_b, wo_b, (void*)out, S_LEN, HID, HID);
}

// Round 9
// 482.835 us; speedup vs baseline: 1.6554x; 1.0330x over previous
//
#include <hip/hip_runtime.h>

// ---------------------------------------------------------------------------
// LlamaAttention_Tender: hidden(2048x4096) -> QKV proj -> RoPE -> int8 qdq(K,V)
// -> GQA causal attention (32 q-heads, 8 kv-heads, D=128) -> out proj.
// R11: re-anchor at R7 exactly (best verified 489.6us; R10's defer-max was
//      null-to-negative -> removed) + merge the 5 cast launches into ONE
//      segmented-grid kernel (saves 4 x ~10us launch joints; identical
//      per-thread work, block->region mapping is wave-uniform).
//      GEMMs: 128x192 QKV / 128x128 out-proj, 2 blocks/CU, full fill (R7).
//      Attention: double-buffered global_load_lds staging, 80KB LDS,
//      both-sides XOR swizzle, setprio on MFMA clusters (R7).
// ---------------------------------------------------------------------------

#define S_LEN 2048
#define HID 4096
#define NH 32
#define NKV 8
#define HD 128
#define QKV_N 6144   // 4096 q + 1024 k + 1024 v

typedef __bf16 bf16x8 __attribute__((ext_vector_type(8)));
typedef float f32x4 __attribute__((ext_vector_type(4)));

__device__ __forceinline__ unsigned short f2b(float f) {
  unsigned int u = __float_as_uint(f);
  u += 0x7fffu + ((u >> 16) & 1u);   // round-to-nearest-even
  return (unsigned short)(u >> 16);
}
__device__ __forceinline__ float b2f(unsigned short h) {
  return __uint_as_float(((unsigned int)h) << 16);
}
// async global->LDS, 16B per lane. LDS dst must be wave-uniform (lane*16 implicit).
__device__ __forceinline__ void gl_lds16(const void* g, void* l) {
  __builtin_amdgcn_global_load_lds(
      (__attribute__((address_space(1))) void*)g,
      (__attribute__((address_space(3))) void*)l, 16, 0, 0);
}
// compiler-opaque LDS b128 read (no alias info -> no auto vmcnt drains).
__device__ __forceinline__ bf16x8 ds_read128(const void* p) {
  bf16x8 r;
  unsigned a = (unsigned)(unsigned long long)
      (__attribute__((address_space(3))) const void*)p;
  asm volatile("ds_read_b128 %0, %1" : "=v"(r) : "v"(a));
  return r;
}
// LDS bank-spread swizzle: permutes 16B chunks within a 128B row; involution.
__device__ __forceinline__ int swz(int row) {
  return ((row & 7) << 4) ^ (((row >> 3) & 1) << 5);
}
// barrier without the __syncthreads vmcnt(0) drain; asm fences stop IR motion
__device__ __forceinline__ void barrier_np() {
  asm volatile("" ::: "memory");
  __builtin_amdgcn_s_barrier();
  asm volatile("" ::: "memory");
}
#define WAITL0                                            \
  do {                                                    \
    asm volatile("s_waitcnt lgkmcnt(0)" ::: "memory");    \
    __builtin_amdgcn_sched_barrier(0);                    \
  } while (0)

// ------------------------------------- merged fp32->bf16 cast (all 5 tensors)
// One launch instead of five. Each block converts 1024 float4 (4096 floats);
// block->region mapping is uniform (no divergence). Region block counts:
// hidden 2048 | wq 4096 | wk 1024 | wv 1024 | wo 4096  -> 12288 blocks.
__global__ __launch_bounds__(256) void cast5_kernel(
    const float* __restrict__ hidden, const float* __restrict__ wq,
    const float* __restrict__ wk, const float* __restrict__ wv,
    const float* __restrict__ wo, unsigned short* __restrict__ hid_b,
    unsigned short* __restrict__ wqkv_b, unsigned short* __restrict__ wo_b) {
  const int b = blockIdx.x;
  const float* src;
  unsigned short* dst;
  int lb;
  if (b < 2048)      { src = hidden; dst = hid_b;             lb = b; }
  else if (b < 6144) { src = wq;     dst = wqkv_b;            lb = b - 2048; }
  else if (b < 7168) { src = wk;     dst = wqkv_b + 16777216; lb = b - 6144; }
  else if (b < 8192) { src = wv;     dst = wqkv_b + 20971520; lb = b - 7168; }
  else               { src = wo;     dst = wo_b;              lb = b - 8192; }
  long base = (long)lb * 1024 + threadIdx.x;
#pragma unroll
  for (int it = 0; it < 4; ++it) {
    long i = base + it * 256;
    float4 v = ((const float4*)src)[i];
    ushort4 o;
    o.x = f2b(v.x); o.y = f2b(v.y); o.z = f2b(v.z); o.w = f2b(v.w);
    ((ushort4*)dst)[i] = o;
  }
}

// --------------------------------- B^T GEMM, 128xBN tile, 4 waves, 2 blocks/CU
// C[M,N] = A[M,K]*B[N,K]^T. 256 thr = 4 waves (2Mx2N), per-wave out 64x(BN/2).
// LDS per buffer: A 16KB + B BN*128B; double-buffered. BK=64, NT=K/64.
// CMODE: 0 = f32 store, 1 = bf16 store.
template <int BN, int CMODE>
__global__ __launch_bounds__(256, 2) void gemm_bt(const unsigned short* __restrict__ A,
                                                  const unsigned short* __restrict__ B,
                                                  void* __restrict__ Cout,
                                                  int M, int N, int K) {
  constexpr int NI = BN / 32;                 // per-wave ni count (6 or 4)
  constexpr int BSTRIDE = 16384 + BN * 128;   // per-buffer LDS bytes
  __shared__ __align__(16) char lds[2 * BSTRIDE];
  const int tid = threadIdx.x;
  const int lane = tid & 63, wave = tid >> 6;
  const int quad = lane >> 4, l16 = lane & 15;
  const int wave_m = wave >> 1, wave_n = wave & 1;
  const long row0 = (long)blockIdx.y * 128;
  const long col0 = (long)blockIdx.x * BN;
  const int NT = K >> 6;
  const long rowstride = (long)K * 2;

  f32x4 acc[4][NI] = {};

  // stage A half-tile (64 rows, 8KB): 2 gl_lds per wave
  auto stageA = [&](int T, int h, int buf) {
    if (T >= NT) return;
    char* dst = lds + buf * BSTRIDE + h * 8192 + wave * 1024;
    const char* src = (const char*)A + (row0 + h * 64) * rowstride + (long)T * 128;
#pragma unroll
    for (int c = 0; c < 2; ++c) {
      int b = c * 4096 + wave * 1024 + lane * 16;
      int r = b >> 7, cb = b & 127;
      gl_lds16(src + (long)r * rowstride + (cb ^ swz(r)), dst + c * 4096);
    }
  };
  // stage B half-tile (BN/2 rows): BN/64 gl_lds per wave
  auto stageB = [&](int T, int h, int buf) {
    if (T >= NT) return;
    char* dst = lds + buf * BSTRIDE + 16384 + h * (BN * 64) + wave * 1024;
    const char* src = (const char*)B + (col0 + h * (BN / 2)) * rowstride + (long)T * 128;
#pragma unroll
    for (int c = 0; c < BN / 64; ++c) {
      int b = c * 4096 + wave * 1024 + lane * 16;
      int r = b >> 7, cb = b & 127;
      gl_lds16(src + (long)r * rowstride + (cb ^ swz(r)), dst + c * 4096);
    }
  };
  // counted vmcnt: HOPS = ops per (A-half + B-half) stage pair = 2 + BN/64
  auto fence_steady = [&]() {
    if (BN == 192) asm volatile("s_waitcnt vmcnt(5)" ::: "memory");
    else           asm volatile("s_waitcnt vmcnt(4)" ::: "memory");
  };

  // prologue: T0 h0, T0 h1, T1 h0 -> fence completes T0 fully, carry = h0(T1)
  stageA(0, 0, 0); stageB(0, 0, 0);
  stageA(0, 1, 0); stageB(0, 1, 0);
  stageA(1, 0, 1); stageB(1, 0, 1);
  fence_steady();

  for (int g = 0; g < NT; ++g) {
    const int buf = g & 1;
    barrier_np();                          // #1: all waves fenced; buf data ready
    stageA(g + 1, 1, buf ^ 1);             // h1 of next tile -> other buffer
    stageB(g + 1, 1, buf ^ 1);

    bf16x8 a[2][4], b[2][NI];
#pragma unroll
    for (int mi = 0; mi < 4; ++mi) {
      int row = wave_m * 64 + mi * 16 + l16;
      const char* rp = lds + buf * BSTRIDE + row * 128;
      int sw = swz(row);
      a[0][mi] = ds_read128(rp + ((quad * 16) ^ sw));
      a[1][mi] = ds_read128(rp + ((64 + quad * 16) ^ sw));
    }
#pragma unroll
    for (int ni = 0; ni < NI; ++ni) {
      int row = wave_n * (BN / 2) + ni * 16 + l16;
      const char* rp = lds + buf * BSTRIDE + 16384 + row * 128;
      int sw = swz(row);
      b[0][ni] = ds_read128(rp + ((quad * 16) ^ sw));
      b[1][ni] = ds_read128(rp + ((64 + quad * 16) ^ sw));
    }
    WAITL0;                                // my reads done
    barrier_np();                          // #2: everyone's reads done
    stageA(g + 2, 0, buf);                 // overwrite h0 of current buf
    stageB(g + 2, 0, buf);

    __builtin_amdgcn_s_setprio(1);
#pragma unroll
    for (int ks = 0; ks < 2; ++ks)
#pragma unroll
      for (int mi = 0; mi < 4; ++mi)
#pragma unroll
        for (int ni = 0; ni < NI; ++ni)
          acc[mi][ni] = __builtin_amdgcn_mfma_f32_16x16x32_bf16(
              a[ks][mi], b[ks][ni], acc[mi][ni], 0, 0, 0);
    __builtin_amdgcn_s_setprio(0);

    if (g + 2 < NT) fence_steady();
    else            asm volatile("s_waitcnt vmcnt(0)" ::: "memory");
  }

  // epilogue: C write (C/D layout: col=l16, row=quad*4+r per 16x16 frag)
#pragma unroll
  for (int mi = 0; mi < 4; ++mi)
#pragma unroll
    for (int ni = 0; ni < NI; ++ni)
#pragma unroll
      for (int r = 0; r < 4; ++r) {
        long row = row0 + wave_m * 64 + mi * 16 + quad * 4 + r;
        long col = col0 + wave_n * (BN / 2) + ni * 16 + l16;
        float v = acc[mi][ni][r];
        if (CMODE == 1) ((unsigned short*)Cout)[row * N + col] = f2b(v);
        else            ((float*)Cout)[row * N + col] = v;
      }
}

// ------------------------------------------- RoPE + sym int8 quant-dequant + split
// qkv[2048][6144] bf16 -> Qb[32][2048][128], Kb[8][2048][128], Vb[8][2048][128]
__global__ __launch_bounds__(256) void postproc(const unsigned short* __restrict__ qkv,
                                                const int* __restrict__ pos_ids,
                                                unsigned short* __restrict__ Qb,
                                                unsigned short* __restrict__ Kb,
                                                unsigned short* __restrict__ Vb) {
  const int s = blockIdx.x;
  const int lane = threadIdx.x & 63, wave = threadIdx.x >> 6;
  const float pos = (float)pos_ids[s];
  // inv_freq = 10000^(-lane/64) = exp(-lane * ln(10000)/64); pair (d, d+64)
  const float invf = expf(-(float)lane * 0.14391156831212787f);
  const float ang = pos * invf;
  const float ca = cosf(ang), sa = sinf(ang);

  for (int r = wave; r < 48; r += 4) {
    if (r < 32) {                 // Q head r: rope only
      const unsigned short* src = qkv + (long)s * QKV_N + r * HD;
      float x0 = b2f(src[lane]), x1 = b2f(src[lane + 64]);
      unsigned short* dst = Qb + ((long)r * S_LEN + s) * HD;
      dst[lane]      = f2b(x0 * ca - x1 * sa);
      dst[lane + 64] = f2b(x1 * ca + x0 * sa);
    } else if (r < 40) {          // K head r-32: rope then quant-dequant
      int h = r - 32;
      const unsigned short* src = qkv + (long)s * QKV_N + 4096 + h * HD;
      float x0 = b2f(src[lane]), x1 = b2f(src[lane + 64]);
      float y0 = x0 * ca - x1 * sa;
      float y1 = x1 * ca + x0 * sa;
      float m = fmaxf(fabsf(y0), fabsf(y1));
      for (int off = 32; off; off >>= 1) m = fmaxf(m, __shfl_xor(m, off, 64));
      float scale = fmaxf(m / 127.0f, 1e-9f);
      float q0 = fminf(fmaxf(rintf(y0 / scale), -128.f), 127.f);
      float q1 = fminf(fmaxf(rintf(y1 / scale), -128.f), 127.f);
      unsigned short* dst = Kb + ((long)h * S_LEN + s) * HD;
      dst[lane]      = f2b(q0 * scale);
      dst[lane + 64] = f2b(q1 * scale);
    } else {                      // V head r-40: quant-dequant only
      int h = r - 40;
      const unsigned short* src = qkv + (long)s * QKV_N + 5120 + h * HD;
      float x0 = b2f(src[lane]), x1 = b2f(src[lane + 64]);
      float m = fmaxf(fabsf(x0), fabsf(x1));
      for (int off = 32; off; off >>= 1) m = fmaxf(m, __shfl_xor(m, off, 64));
      float scale = fmaxf(m / 127.0f, 1e-9f);
      float q0 = fminf(fmaxf(rintf(x0 / scale), -128.f), 127.f);
      float q1 = fminf(fmaxf(rintf(x1 / scale), -128.f), 127.f);
      unsigned short* dst = Vb + ((long)h * S_LEN + s) * HD;
      dst[lane]      = f2b(q0 * scale);
      dst[lane + 64] = f2b(q1 * scale);
    }
  }
}

// -------------------------------------------------- V transpose: [h][s][d]->[h][d][s]
__global__ __launch_bounds__(256) void transpose_v(const unsigned short* __restrict__ Vb,
                                                   unsigned short* __restrict__ Vtb) {
  __shared__ unsigned short t[64][136];
  const int h = blockIdx.x >> 5, st = blockIdx.x & 31;
  const int tid = threadIdx.x;
  const long vbase = (long)h * S_LEN * HD;
#pragma unroll
  for (int p = 0; p < 8; ++p) {
    int e = p * 1024 + tid * 4;
    int sl = e >> 7, d = e & 127;
    ushort4 v = *(const ushort4*)(Vb + vbase + (long)(st * 64 + sl) * HD + d);
    t[sl][d] = v.x; t[sl][d + 1] = v.y; t[sl][d + 2] = v.z; t[sl][d + 3] = v.w;
  }
  __syncthreads();
  const long tbase = (long)h * HD * S_LEN;
#pragma unroll
  for (int p = 0; p < 8; ++p) {
    int o = p * 1024 + tid * 4;
    int d = o >> 6, sl = o & 63;
    ushort4 v;
    v.x = t[sl][d]; v.y = t[sl + 1][d]; v.z = t[sl + 2][d]; v.w = t[sl + 3][d];
    *(ushort4*)(Vtb + tbase + (long)d * S_LEN + st * 64 + sl) = v;
  }
}

// ------------------------------------------------------------- flash attention
// Block = (head, 128-row q-tile), 4 waves x 32 q-rows. KVBLK=64.
// R7 structure (proven): K tile [64 keys][128 d] and Vt tile [128 d][64 keys]
// staged in LDS via global_load_lds, double-buffered 2-phase:
//   __syncthreads (drains stage) -> issue stage(t+1) -> compute(t).
// XOR swizzle on K/Vt/Ps applied BOTH sides (pre-swizzled global source,
// swizzled ds_read/ds_write). LDS: K 2x16K + Vt 2x16K + Ps 16K = 80 KB.
// Complementary qt pairing: steps/pair = (2qt+2)+(2(15-qt)+2) = 34, balanced.
__global__ __launch_bounds__(256, 2) void attn_kernel(const unsigned short* __restrict__ Qb,
                                                      const unsigned short* __restrict__ Kb,
                                                      const unsigned short* __restrict__ Vtb,
                                                      unsigned short* __restrict__ Ob) {
  __shared__ __align__(16) char lds[81920];
  // layout: K buf0 @0, K buf1 @16384, V buf0 @32768, V buf1 @49152, Ps @65536

  const int bx = blockIdx.x;
  const int p8 = bx & 1;
  const int g = (bx >> 1) & 7;
  const int b8 = bx >> 8;
  const int qt = (p8 ^ b8) ? (15 - g) : g;
  const int h = ((bx >> 4) & 15) + 16 * b8;
  const int hk = h >> 2;                        // GQA: 4 q-heads per kv-head
  const int tid = threadIdx.x;
  const int lane = tid & 63, wave = tid >> 6;
  const int quad = lane >> 4, l16 = lane & 15;

  // Q fragments for this wave's 32 rows (A-operand layout), from global
  bf16x8 qf[2][4];
  {
    const unsigned short* qb =
        Qb + ((long)h * S_LEN + qt * 128 + wave * 32 + l16) * HD + quad * 8;
#pragma unroll
    for (int mi = 0; mi < 2; ++mi)
#pragma unroll
      for (int ks = 0; ks < 4; ++ks)
        qf[mi][ks] = *(const bf16x8*)(qb + mi * 16 * HD + ks * 32);
  }

  f32x4 O[2][8] = {};
  float mrow[2][4], lrow[2][4];
#pragma unroll
  for (int mi = 0; mi < 2; ++mi)
#pragma unroll
    for (int r = 0; r < 4; ++r) { mrow[mi][r] = -1e30f; lrow[mi][r] = 0.f; }

  const char* Kg = (const char*)(Kb + (long)hk * S_LEN * HD);
  const char* Vg = (const char*)(Vtb + (long)hk * HD * S_LEN);
  char* PsB = lds + 65536;
  const float sscale = 0.08838834764831845f;  // 1/sqrt(128)
  const int nsteps = 2 * qt + 2;              // 64-key steps

  // stage one 64-key K tile (16 KB, contiguous rows in global) into buf
  auto stageK = [&](int step, int buf) {
    char* dst = lds + buf * 16384 + wave * 1024;
    const char* src = Kg + (long)step * 16384;
#pragma unroll
    for (int c = 0; c < 4; ++c) {
      int f = c * 4096 + tid * 16;
      int row = f >> 8, wb = f & 255;
      gl_lds16(src + row * 256 + (wb ^ swz(row)), dst + c * 4096);
    }
  };
  // stage one Vt tile [128 d][64 keys] (d-rows strided 4096B in global)
  auto stageV = [&](int step, int buf) {
    char* dst = lds + 32768 + buf * 16384 + wave * 1024;
    const char* src = Vg + (long)step * 128;
#pragma unroll
    for (int c = 0; c < 4; ++c) {
      int f = c * 4096 + tid * 16;
      int d = f >> 7, wb = f & 127;
      gl_lds16(src + (long)d * (S_LEN * 2) + (wb ^ swz(d)), dst + c * 4096);
    }
  };

  stageK(0, 0);
  stageV(0, 0);

  for (int t = 0; t < nsteps; ++t) {
    __syncthreads();   // drains this wave's stage (vmcnt 0) + syncs all waves
    if (t + 1 < nsteps) {
      stageK(t + 1, (t + 1) & 1);
      stageV(t + 1, (t + 1) & 1);
    }
    const char* Ks = lds + (t & 1) * 16384;
    const char* Vs = lds + 32768 + (t & 1) * 16384;

    // ---- S = Q K^T over 64 keys (4 ni of 16)
    f32x4 S[2][4] = {};
    __builtin_amdgcn_s_setprio(1);
#pragma unroll
    for (int ni = 0; ni < 4; ++ni) {
      const int row = ni * 16 + l16;
      const char* kr = Ks + row * 256;
      const int sw = swz(row);
      const int q16 = quad * 16;
      bf16x8 kf0 = *(const bf16x8*)(kr + ((q16 + 0)   ^ sw));
      bf16x8 kf1 = *(const bf16x8*)(kr + ((q16 + 64)  ^ sw));
      bf16x8 kf2 = *(const bf16x8*)(kr + ((q16 + 128) ^ sw));
      bf16x8 kf3 = *(const bf16x8*)(kr + ((q16 + 192) ^ sw));
      S[0][ni] = __builtin_amdgcn_mfma_f32_16x16x32_bf16(qf[0][0], kf0, S[0][ni], 0, 0, 0);
      S[1][ni] = __builtin_amdgcn_mfma_f32_16x16x32_bf16(qf[1][0], kf0, S[1][ni], 0, 0, 0);
      S[0][ni] = __builtin_amdgcn_mfma_f32_16x16x32_bf16(qf[0][1], kf1, S[0][ni], 0, 0, 0);
      S[1][ni] = __builtin_amdgcn_mfma_f32_16x16x32_bf16(qf[1][1], kf1, S[1][ni], 0, 0, 0);
      S[0][ni] = __builtin_amdgcn_mfma_f32_16x16x32_bf16(qf[0][2], kf2, S[0][ni], 0, 0, 0);
      S[1][ni] = __builtin_amdgcn_mfma_f32_16x16x32_bf16(qf[1][2], kf2, S[1][ni], 0, 0, 0);
      S[0][ni] = __builtin_amdgcn_mfma_f32_16x16x32_bf16(qf[0][3], kf3, S[0][ni], 0, 0, 0);
      S[1][ni] = __builtin_amdgcn_mfma_f32_16x16x32_bf16(qf[1][3], kf3, S[1][ni], 0, 0, 0);
    }
    __builtin_amdgcn_s_setprio(0);

    // ---- scale + causal mask + row max
    const bool diag = (t >= 2 * qt);
    const int qrow_base = qt * 128 + wave * 32;
    float rmax[2][4];
#pragma unroll
    for (int mi = 0; mi < 2; ++mi)
#pragma unroll
      for (int r = 0; r < 4; ++r) rmax[mi][r] = -1e30f;
#pragma unroll
    for (int mi = 0; mi < 2; ++mi)
#pragma unroll
      for (int ni = 0; ni < 4; ++ni) {
        int col = t * 64 + ni * 16 + l16;
#pragma unroll
        for (int r = 0; r < 4; ++r) {
          int row = qrow_base + mi * 16 + quad * 4 + r;
          float v = S[mi][ni][r] * sscale;
          if (diag && col > row) v = -1e9f;
          S[mi][ni][r] = v;
          rmax[mi][r] = fmaxf(rmax[mi][r], v);
        }
      }
    float alpha[2][4], rsum[2][4];
#pragma unroll
    for (int mi = 0; mi < 2; ++mi)
#pragma unroll
      for (int r = 0; r < 4; ++r) {
        float v = rmax[mi][r];
        v = fmaxf(v, __shfl_xor(v, 1, 64));
        v = fmaxf(v, __shfl_xor(v, 2, 64));
        v = fmaxf(v, __shfl_xor(v, 4, 64));
        v = fmaxf(v, __shfl_xor(v, 8, 64));
        float mnew = fmaxf(mrow[mi][r], v);
        alpha[mi][r] = __expf(mrow[mi][r] - mnew);
        mrow[mi][r] = mnew;
        rsum[mi][r] = 0.f;
      }

    // ---- P = exp(S - m) -> wave-local swizzled LDS rows, accumulate sums
#pragma unroll
    for (int mi = 0; mi < 2; ++mi)
#pragma unroll
      for (int ni = 0; ni < 4; ++ni)
#pragma unroll
        for (int r = 0; r < 4; ++r) {
          float p = __expf(S[mi][ni][r] - mrow[mi][r]);
          rsum[mi][r] += p;
          int prow = wave * 32 + mi * 16 + quad * 4 + r;
          int pcol2 = (ni * 16 + l16) * 2;
          *(unsigned short*)(PsB + prow * 128 + (pcol2 ^ swz(prow))) = f2b(p);
        }
#pragma unroll
    for (int mi = 0; mi < 2; ++mi)
#pragma unroll
      for (int r = 0; r < 4; ++r) {
        float v = rsum[mi][r];
        v += __shfl_xor(v, 1, 64);
        v += __shfl_xor(v, 2, 64);
        v += __shfl_xor(v, 4, 64);
        v += __shfl_xor(v, 8, 64);
        lrow[mi][r] = lrow[mi][r] * alpha[mi][r] + v;
      }
#pragma unroll
    for (int mi = 0; mi < 2; ++mi)
#pragma unroll
      for (int ni = 0; ni < 8; ++ni)
#pragma unroll
        for (int r = 0; r < 4; ++r) O[mi][ni][r] *= alpha[mi][r];

    // ---- O += P V : P A-frags from wave-local LDS, Vt B-frags from LDS tile
    bf16x8 pf[2][2];
#pragma unroll
    for (int mi = 0; mi < 2; ++mi)
#pragma unroll
      for (int ks2 = 0; ks2 < 2; ++ks2) {
        int prow = wave * 32 + mi * 16 + l16;
        pf[mi][ks2] = *(const bf16x8*)(PsB + prow * 128 +
                                       ((ks2 * 64 + quad * 16) ^ swz(prow)));
      }
    __builtin_amdgcn_s_setprio(1);
#pragma unroll
    for (int ni = 0; ni < 8; ++ni) {
      const int row = ni * 16 + l16;
      const char* vr = Vs + row * 128;
      const int sw = swz(row);
      const int q16 = quad * 16;
      bf16x8 vf0 = *(const bf16x8*)(vr + ((q16 + 0)  ^ sw));
      bf16x8 vf1 = *(const bf16x8*)(vr + ((q16 + 64) ^ sw));
      O[0][ni] = __builtin_amdgcn_mfma_f32_16x16x32_bf16(pf[0][0], vf0, O[0][ni], 0, 0, 0);
      O[1][ni] = __builtin_amdgcn_mfma_f32_16x16x32_bf16(pf[1][0], vf0, O[1][ni], 0, 0, 0);
      O[0][ni] = __builtin_amdgcn_mfma_f32_16x16x32_bf16(pf[0][1], vf1, O[0][ni], 0, 0, 0);
      O[1][ni] = __builtin_amdgcn_mfma_f32_16x16x32_bf16(pf[1][1], vf1, O[1][ni], 0, 0, 0);
    }
    __builtin_amdgcn_s_setprio(0);
  }

  // normalize + store bf16 at [s][h*128+d]
#pragma unroll
  for (int mi = 0; mi < 2; ++mi)
#pragma unroll
    for (int r = 0; r < 4; ++r) {
      float inv = 1.0f / lrow[mi][r];
      long srow = qt * 128 + wave * 32 + mi * 16 + quad * 4 + r;
#pragma unroll
      for (int ni = 0; ni < 8; ++ni) {
        long col = (long)h * HD + ni * 16 + l16;
        Ob[srow * (long)HID + col] = f2b(O[mi][ni][r] * inv);
      }
    }
}

// ---------------------------------------------------------------------------
extern "C" void kernel_launch(void* const* d_in, const int* in_sizes, int n_in,
                              void* d_out, int out_size, void* d_ws, size_t ws_size,
                              hipStream_t stream) {
  const float* hidden = (const float*)d_in[0];
  const float* wq = (const float*)d_in[1];
  const float* wk = (const float*)d_in[2];
  const float* wv = (const float*)d_in[3];
  const float* wo = (const float*)d_in[4];
  const int* pos = (const int*)d_in[5];
  float* out = (float*)d_out;

  // workspace layout (bytes); total 138,412,032. Overlays: Qb=hid_b (hid dead
  // after GEMM1), attn_b=qkv_b (qkv dead after postproc).
  char* ws = (char*)d_ws;
  unsigned short* wqkv_b = (unsigned short*)(ws);               // 50,331,648
  unsigned short* wo_b   = (unsigned short*)(ws + 50331648);    // 33,554,432
  unsigned short* hid_b  = (unsigned short*)(ws + 83886080);    // 16,777,216
  unsigned short* qkv_b  = (unsigned short*)(ws + 100663296);   // 25,165,824
  unsigned short* Kb     = (unsigned short*)(ws + 125829120);   //  4,194,304
  unsigned short* Vb     = (unsigned short*)(ws + 130023424);   //  4,194,304
  unsigned short* Vtb    = (unsigned short*)(ws + 134217728);   //  4,194,304
  unsigned short* Qb     = hid_b;
  unsigned short* attn_b = qkv_b;

  // all 5 fp32->bf16 casts in ONE launch (saves 4 launch joints)
  cast5_kernel<<<12288, 256, 0, stream>>>(hidden, wq, wk, wv, wo,
                                          hid_b, wqkv_b, wo_b);

  // QKV: 128x192 tiles -> grid 32x16 = 512 blocks = 2/CU, 100% fill
  gemm_bt<192, 1><<<dim3(QKV_N / 192, S_LEN / 128), 256, 0, stream>>>(
      hid_b, wqkv_b, (void*)qkv_b, S_LEN, QKV_N, HID);

  postproc<<<S_LEN, 256, 0, stream>>>(qkv_b, pos, Qb, Kb, Vb);
  transpose_v<<<NKV * 32, 256, 0, stream>>>(Vb, Vtb);
  attn_kernel<<<NH * 16, 256, 0, stream>>>(Qb, Kb, Vtb, attn_b);

  // out-proj: 128x128 tiles -> grid 32x16 = 512 blocks = 2/CU, 100% fill
  gemm_bt<128, 0><<<dim3(HID / 128, S_LEN / 128), 256, 0, stream>>>(
      attn_b, wo_b, (void*)out, S_LEN, HID, HID);
}